// Round 1
// 2401.117 us; speedup vs baseline: 1.0481x; 1.0481x over previous
//
#include <hip/hip_runtime.h>
#include <hip/hip_bf16.h>

// VQ-VAE forward. Index path: fp32-per-op semantics w/ fp64 internal accumulation
// via f64 MFMA for z (encoder). Score/argmin path REPLACED (R8): two fp16-MFMA
// sweeps (approx min -> candidate window) + exact f64 refine on ~25k candidate
// pairs, reproducing the previous all-f64 argmin bit-identically via a rigorous
// Cauchy-Schwarz error window. Decoder: bf16 MFMA.
// Outputs (flat fp32): recon[16384*1024], loss[1], indices-as-float[16384].

#define B_    16384
#define INDIM 1024
#define HID   2048
#define KCB   8192
#define DDIM  128

#define CAND_CAP 2000000u

typedef __bf16    bf16x8   __attribute__((ext_vector_type(8)));
typedef float     floatx4  __attribute__((ext_vector_type(4)));
typedef double    doublex4 __attribute__((ext_vector_type(4)));
typedef _Float16  half8    __attribute__((ext_vector_type(8)));

__device__ __forceinline__ unsigned long long pack_key(float d, int code)
{
    unsigned int u = __float_as_uint(d);
    u = (u & 0x80000000u) ? ~u : (u | 0x80000000u);   // total order matching float <
    return ((unsigned long long)u << 32) | (unsigned int)code;
}

__device__ __forceinline__ float unpack_d(unsigned long long key)
{
    unsigned int u = (unsigned int)(key >> 32);
    u = (u & 0x80000000u) ? (u ^ 0x80000000u) : ~u;
    return __uint_as_float(u);
}

// Async global->LDS, 16 B per lane. LDS dest: wave-uniform base + lane*16.
__device__ __forceinline__ void gll16(const float* g, float* l)
{
    __builtin_amdgcn_global_load_lds(
        (const __attribute__((address_space(1))) void*)g,
        (__attribute__((address_space(3))) void*)l, 16, 0, 0);
}

// ---------------------------------------------------------------------------
// fp32-in GEMM, f64 MFMA accumulate, single fp32 rounding (+opt relu).
// A [M][K] row-major, BT [N][K] row-major (pre-transposed). BM=128 BN=64 BK=32.
// 4 waves 2x2, wave tile 64x32 via 4x2 mfma_f64_16x16x4. m97-style 2-barrier
// K-loop with global_load_lds; LDS fp32 packed rows of 32 floats, chunk c of
// row r stored at position c ^ (r&7)  -> all reads <=2-way bank aliasing.
// ---------------------------------------------------------------------------
template <int ACT>
__launch_bounds__(256)
__global__ void gemm_f64_gll(const float* __restrict__ A, const float* __restrict__ BT,
                             const float* __restrict__ bias, float* __restrict__ Cout,
                             int M, int N, int K)
{
    __shared__ float As[128 * 32];
    __shared__ float Bs[64 * 32];

    const int t    = threadIdx.x;
    const int m0   = blockIdx.y * 128, n0 = blockIdx.x * 64;
    const int wave = t >> 6, lane = t & 63;
    const int wr   = (wave >> 1) * 64, wc = (wave & 1) * 32;
    const int quad = lane >> 4, l16 = lane & 15;
    const int lr   = lane >> 3;                 // row within 8-row staging group
    const int lc   = ((lane & 7) ^ lr) * 4;     // swizzled global col (floats)

    // Layout probe: self-correcting for any bijective C/D lane mapping.
    doublex4 p0 = {0.0, 0.0, 0.0, 0.0};
    doublex4 prow = __builtin_amdgcn_mfma_f64_16x16x4f64((double)l16, 1.0, p0, 0, 0, 0);
    doublex4 pcol = __builtin_amdgcn_mfma_f64_16x16x4f64(1.0, (double)l16, p0, 0, 0, 0);
    int rowmap[4], colmap[4];
#pragma unroll
    for (int r = 0; r < 4; ++r) {
        rowmap[r] = (int)(prow[r] * 0.25);
        colmap[r] = (int)(pcol[r] * 0.25);
    }

    doublex4 acc[4][2];
#pragma unroll
    for (int i = 0; i < 4; ++i)
#pragma unroll
        for (int j = 0; j < 2; ++j) acc[i][j] = (doublex4){0.0, 0.0, 0.0, 0.0};

    for (int k0 = 0; k0 < K; k0 += 32) {
        __syncthreads();   // previous compute done -> LDS reusable
#pragma unroll
        for (int s = 0; s < 4; ++s) {          // A: wave covers 32 rows
            int r = wave * 32 + s * 8;
            gll16(A + (size_t)(m0 + r + lr) * K + k0 + lc, &As[r * 32]);
        }
#pragma unroll
        for (int s = 0; s < 2; ++s) {          // B: wave covers 16 rows
            int r = wave * 16 + s * 8;
            gll16(BT + (size_t)(n0 + r + lr) * K + k0 + lc, &Bs[r * 32]);
        }
        __syncthreads();   // deposits visible (compiler drains vmcnt)
#pragma unroll
        for (int ks = 0; ks < 32; ks += 4) {
            const int cbase = (ks >> 2) ^ (l16 & 7);   // swizzled chunk
            double a[4], b[2];
#pragma unroll
            for (int i = 0; i < 4; ++i)
                a[i] = (double)As[(wr + i * 16 + l16) * 32 + cbase * 4 + quad];
#pragma unroll
            for (int j = 0; j < 2; ++j)
                b[j] = (double)Bs[(wc + j * 16 + l16) * 32 + cbase * 4 + quad];
#pragma unroll
            for (int i = 0; i < 4; ++i)
#pragma unroll
                for (int j = 0; j < 2; ++j)
                    acc[i][j] = __builtin_amdgcn_mfma_f64_16x16x4f64(a[i], b[j], acc[i][j], 0, 0, 0);
        }
    }

#pragma unroll
    for (int i = 0; i < 4; ++i)
#pragma unroll
        for (int j = 0; j < 2; ++j)
#pragma unroll
            for (int r = 0; r < 4; ++r) {
                int row = m0 + wr + i * 16 + rowmap[r];
                int col = n0 + wc + j * 16 + colmap[r];
                float f = (float)(acc[i][j][r] + (double)bias[col]);  // single fp32 round
                if (ACT == 1) f = fmaxf(f, 0.f);
                Cout[(size_t)row * N + col] = f;
            }
}

// ---------------------------------------------------------------------------
// rownorm32[k] = fl32( sum_fp64( fl32(row[k][d]^2) ) ). One wave per row.
// ---------------------------------------------------------------------------
__global__ void rownorm_kernel(const float* __restrict__ M, float* __restrict__ nrm)
{
    int k = blockIdx.x * 4 + (threadIdx.x >> 6);
    int lane = threadIdx.x & 63;
    float2 c = *(const float2*)(M + (size_t)k * DDIM + lane * 2);
    float q0 = c.x * c.x;
    float q1 = c.y * c.y;
    double s = (double)q0 + (double)q1;
#pragma unroll
    for (int off = 32; off > 0; off >>= 1) s += __shfl_down(s, off);
    if (lane == 0) nrm[k] = (float)s;
}

// max over cn32 (one block).
__global__ void cnmax_kernel(const float* __restrict__ cn, float* __restrict__ out)
{
    __shared__ float red[4];
    int t = threadIdx.x;
    float m = 0.f;
    for (int i = t; i < KCB; i += 256) m = fmaxf(m, cn[i]);
#pragma unroll
    for (int off = 32; off > 0; off >>= 1) m = fmaxf(m, __shfl_down(m, off));
    if ((t & 63) == 0) red[t >> 6] = m;
    __syncthreads();
    if (t == 0) out[0] = fmaxf(fmaxf(red[0], red[1]), fmaxf(red[2], red[3]));
}

// fp32 -> fp16 (optionally scaled by an exact power of two), 8 elems/thread.
__global__ void cvt_half(const float* __restrict__ in, _Float16* __restrict__ out,
                         float scale, int n8)
{
    int i = blockIdx.x * 256 + threadIdx.x;
    if (i >= n8) return;
    const float4 a = *(const float4*)(in + (size_t)i * 8);
    const float4 b = *(const float4*)(in + (size_t)i * 8 + 4);
    half8 h;
    h[0] = (_Float16)(a.x * scale); h[1] = (_Float16)(a.y * scale);
    h[2] = (_Float16)(a.z * scale); h[3] = (_Float16)(a.w * scale);
    h[4] = (_Float16)(b.x * scale); h[5] = (_Float16)(b.y * scale);
    h[6] = (_Float16)(b.z * scale); h[7] = (_Float16)(b.w * scale);
    *(half8*)(out + (size_t)i * 8) = h;
}

// ---------------------------------------------------------------------------
// LEGACY exact f64 score (kept for fallback, not launched).
// ---------------------------------------------------------------------------
__launch_bounds__(256)
__global__ void score_argmin_gll(const float* __restrict__ z, const float* __restrict__ cb,
                                 const float* __restrict__ nz32, const float* __restrict__ cn32,
                                 unsigned long long* __restrict__ gbest)
{
    __shared__ float zs[64 * 32];
    __shared__ float cs[128 * 32];
    __shared__ unsigned long long best[64];

    const int t    = threadIdx.x;
    const int m0   = blockIdx.y * 64;    // rows
    const int n0   = blockIdx.x * 128;   // codes
    const int wave = t >> 6, lane = t & 63;
    const int wr   = (wave >> 1) * 32, wc = (wave & 1) * 64;
    const int quad = lane >> 4, l16 = lane & 15;
    const int lr   = lane >> 3;
    const int lc   = ((lane & 7) ^ lr) * 4;

    if (t < 64) best[t] = ~0ull;

    doublex4 p0 = {0.0, 0.0, 0.0, 0.0};
    doublex4 prow = __builtin_amdgcn_mfma_f64_16x16x4f64((double)l16, 1.0, p0, 0, 0, 0);
    doublex4 pcol = __builtin_amdgcn_mfma_f64_16x16x4f64(1.0, (double)l16, p0, 0, 0, 0);
    int rowmap[4], colmap[4];
#pragma unroll
    for (int r = 0; r < 4; ++r) {
        rowmap[r] = (int)(prow[r] * 0.25);
        colmap[r] = (int)(pcol[r] * 0.25);
    }

    doublex4 acc[2][4];
#pragma unroll
    for (int i = 0; i < 2; ++i)
#pragma unroll
        for (int j = 0; j < 4; ++j) acc[i][j] = (doublex4){0.0, 0.0, 0.0, 0.0};

    for (int k0 = 0; k0 < DDIM; k0 += 32) {
        __syncthreads();
#pragma unroll
        for (int s = 0; s < 2; ++s) {
            int r = wave * 16 + s * 8;
            gll16(z + (size_t)(m0 + r + lr) * DDIM + k0 + lc, &zs[r * 32]);
        }
#pragma unroll
        for (int s = 0; s < 4; ++s) {
            int r = wave * 32 + s * 8;
            gll16(cb + (size_t)(n0 + r + lr) * DDIM + k0 + lc, &cs[r * 32]);
        }
        __syncthreads();
#pragma unroll
        for (int ks = 0; ks < 32; ks += 4) {
            const int cbase = (ks >> 2) ^ (l16 & 7);
            double a[2], b[4];
#pragma unroll
            for (int i = 0; i < 2; ++i)
                a[i] = (double)zs[(wr + i * 16 + l16) * 32 + cbase * 4 + quad];
#pragma unroll
            for (int j = 0; j < 4; ++j)
                b[j] = (double)cs[(wc + j * 16 + l16) * 32 + cbase * 4 + quad];
#pragma unroll
            for (int i = 0; i < 2; ++i)
#pragma unroll
                for (int j = 0; j < 4; ++j)
                    acc[i][j] = __builtin_amdgcn_mfma_f64_16x16x4f64(a[i], b[j], acc[i][j], 0, 0, 0);
        }
    }

#pragma unroll
    for (int i = 0; i < 2; ++i)
#pragma unroll
        for (int r = 0; r < 4; ++r) {
            int   lrow = wr + i * 16 + rowmap[r];
            float nz   = nz32[m0 + lrow];
            float bd   = 3.4e38f; int bc = 0x7fffffff;
#pragma unroll
            for (int j = 0; j < 4; ++j) {
                int   code = n0 + wc + j * 16 + colmap[r];
                float s32  = (float)acc[i][j][r];
                float d    = (nz - 2.0f * s32) + cn32[code];
                if (d < bd || (d == bd && code < bc)) { bd = d; bc = code; }
            }
            atomicMin(&best[lrow], pack_key(bd, bc));
        }
    __syncthreads();
    if (t < 64) atomicMin(&gbest[m0 + t], best[t]);
}

// ---------------------------------------------------------------------------
// fp16 approximate score sweeps. 128x128 tile, full K=128 staged once.
// LDS XOR-swizzled ((row&7)<<1 on 16B chunks) via per-lane PRE-SWIZZLED global
// source (gll dest stays linear). EMIT=0: per-row approx min -> gbestA.
// EMIT=1: emit candidates with d_a <= minA + W(row) to the list.
// Window W is a rigorous bound: |d_a - d_exact| <= 2*B_s + chain/FTZ cushion,
// B_s <= (2^-11 + accum) * sqrt(nz*cnmax) (Cauchy-Schwarz), so the true
// argmin (incl. exact ties) is always inside the window.
// ---------------------------------------------------------------------------
template <int EMIT>
__launch_bounds__(256)
__global__ void score_sweep(const _Float16* __restrict__ zh, const _Float16* __restrict__ ch,
                            const float* __restrict__ nz32, const float* __restrict__ cn32,
                            unsigned long long* __restrict__ gbestA,
                            const float* __restrict__ cnmaxp,
                            unsigned* __restrict__ listCnt, unsigned* __restrict__ list)
{
    __shared__ __align__(16) _Float16 As[128 * 128];
    __shared__ __align__(16) _Float16 Bs[128 * 128];
    __shared__ unsigned long long best[128];

    const int t    = threadIdx.x;
    const int m0   = blockIdx.y * 128;   // rows
    const int n0   = blockIdx.x * 128;   // codes
    const int wave = t >> 6, lane = t & 63;
    const int wr   = (wave >> 1) * 64, wc = (wave & 1) * 64;
    const int quad = lane >> 4, l16 = lane & 15;

    if (EMIT == 0 && t < 128) best[t] = ~0ull;

    // stage: each wave covers 32 rows of A and 32 rows of B, 4 rows per gll16.
    const int srow = lane >> 4;          // row within 4-row group
    const int sc   = lane & 15;          // 16B chunk within row
#pragma unroll
    for (int s = 0; s < 8; ++s) {
        const int rbase = wave * 32 + s * 4;
        const int ra = rbase + srow;
        const int cs = sc ^ ((ra & 7) << 1);   // pre-swizzled SOURCE chunk
        gll16((const float*)(zh + (size_t)(m0 + ra) * 128 + cs * 8),
              (float*)&As[rbase * 128]);
        gll16((const float*)(ch + (size_t)(n0 + ra) * 128 + cs * 8),
              (float*)&Bs[rbase * 128]);
    }
    __syncthreads();   // drains vmcnt

    floatx4 acc[4][4];
#pragma unroll
    for (int i = 0; i < 4; ++i)
#pragma unroll
        for (int j = 0; j < 4; ++j) acc[i][j] = (floatx4){0.f, 0.f, 0.f, 0.f};

#pragma unroll
    for (int ks = 0; ks < 4; ++ks) {
        half8 af[4], bfr[4];
#pragma unroll
        for (int i = 0; i < 4; ++i) {
            const int rl = wr + i * 16 + l16;
            const int cc = (ks * 4 + quad) ^ ((rl & 7) << 1);
            af[i] = *(const half8*)&As[rl * 128 + cc * 8];
        }
#pragma unroll
        for (int j = 0; j < 4; ++j) {
            const int rl = wc + j * 16 + l16;
            const int cc = (ks * 4 + quad) ^ ((rl & 7) << 1);
            bfr[j] = *(const half8*)&Bs[rl * 128 + cc * 8];
        }
#pragma unroll
        for (int i = 0; i < 4; ++i)
#pragma unroll
            for (int j = 0; j < 4; ++j)
                acc[i][j] = __builtin_amdgcn_mfma_f32_16x16x32_f16(af[i], bfr[j], acc[i][j], 0, 0, 0);
    }

    const float cnm = *cnmaxp;
#pragma unroll
    for (int i = 0; i < 4; ++i)
#pragma unroll
        for (int r = 0; r < 4; ++r) {
            const int lrow = wr + i * 16 + quad * 4 + r;
            const int grow = m0 + lrow;
            const float nz = nz32[grow];
            if (EMIT) {
                const float minA = unpack_d(gbestA[grow]);
                const float thr  = minA + 2.4e-3f * sqrtf(nz * cnm) + 6.0e-5f;
#pragma unroll
                for (int j = 0; j < 4; ++j) {
                    const int code = n0 + wc + j * 16 + l16;
                    float s = acc[i][j][r] * (1.0f / 4096.0f);
                    float d = (nz - 2.0f * s) + cn32[code];
                    if (d <= thr) {
                        unsigned idx = atomicAdd(listCnt, 1u);
                        if (idx < CAND_CAP)
                            list[idx] = ((unsigned)grow << 13) | (unsigned)code;
                    }
                }
            } else {
                float bd = 3.4e38f; int bc = 0x7fffffff;
#pragma unroll
                for (int j = 0; j < 4; ++j) {
                    const int code = n0 + wc + j * 16 + l16;
                    float s = acc[i][j][r] * (1.0f / 4096.0f);
                    float d = (nz - 2.0f * s) + cn32[code];
                    if (d < bd || (d == bd && code < bc)) { bd = d; bc = code; }
                }
                atomicMin(&best[lrow], pack_key(bd, bc));
            }
        }

    if (EMIT == 0) {
        __syncthreads();
        if (t < 128) atomicMin(&gbestA[m0 + t], best[t]);
    }
}

// Exact refine: one wave per candidate pair. Reproduces the legacy exact
// semantics: s32 = fl32(f64 sum(z*c)); d = fl32(fl32(nz-2*s32)+cn); packed min.
__launch_bounds__(256)
__global__ void refine_kernel(const float* __restrict__ z, const float* __restrict__ cb,
                              const float* __restrict__ nz32, const float* __restrict__ cn32,
                              const unsigned* __restrict__ listCnt,
                              const unsigned* __restrict__ list,
                              unsigned long long* __restrict__ gbest)
{
    unsigned cnt = *listCnt;
    if (cnt > CAND_CAP) cnt = CAND_CAP;
    const int lane = threadIdx.x & 63;
    for (unsigned p = blockIdx.x * 4 + (threadIdx.x >> 6); p < cnt; p += gridDim.x * 4) {
        const unsigned e = list[p];
        const int r = (int)(e >> 13), k = (int)(e & 8191u);
        float2 zv = *(const float2*)(z  + (size_t)r * DDIM + lane * 2);
        float2 cv = *(const float2*)(cb + (size_t)k * DDIM + lane * 2);
        double s = (double)zv.x * (double)cv.x + (double)zv.y * (double)cv.y;
#pragma unroll
        for (int off = 32; off > 0; off >>= 1) s += __shfl_down(s, off);
        if (lane == 0) {
            float s32 = (float)s;
            float d = (nz32[r] - 2.0f * s32) + cn32[k];
            atomicMin(&gbest[r], pack_key(d, k));
        }
    }
}

__global__ void init_gbest(unsigned long long* __restrict__ g)
{
    g[blockIdx.x * 256 + threadIdx.x] = ~0ull;
}

// Gather z_q = codebook[idx] (fp32) and accumulate sum((z_q - z32)^2) in fp64.
__global__ void gather_zq_loss(const float* __restrict__ z, const float* __restrict__ cb,
                               const unsigned long long* __restrict__ gbest,
                               float* __restrict__ zq, double* __restrict__ acc)
{
    int r = blockIdx.x * 4 + (threadIdx.x >> 6);
    int lane = threadIdx.x & 63;
    int k = (int)(gbest[r] & 0xffffffffull);
    float2 zv = *(const float2*)(z  + (size_t)r * DDIM + lane * 2);
    float2 cv = *(const float2*)(cb + (size_t)k * DDIM + lane * 2);
    *(float2*)(zq + (size_t)r * DDIM + lane * 2) = cv;
    double dx = (double)cv.x - (double)zv.x, dy = (double)cv.y - (double)zv.y;
    double s = dx * dx + dy * dy;
#pragma unroll
    for (int off = 32; off > 0; off >>= 1) s += __shfl_down(s, off);
    if (lane == 0) atomicAdd(acc, s);
}

__global__ void init_scalars(double* acc, unsigned* cnt)
{
    if (threadIdx.x == 0 && blockIdx.x == 0) { *acc = 0.0; *cnt = 0u; }
}

__global__ void finalize_kernel(const unsigned long long* __restrict__ gbest,
                                const double* __restrict__ acc, float* __restrict__ out)
{
    int tid = blockIdx.x * 256 + threadIdx.x;
    if (tid < B_) out[16777217 + tid] = (float)(int)(gbest[tid] & 0xffffffffull);
    if (tid == 0) out[16777216] = (float)((*acc) * 1.25 / (double)(B_ * DDIM));
}

// ---------------------------------------------------------------------------
// One-time weight transposes: fp32 [K][N] -> bf16/fp32 [N][K].
// ---------------------------------------------------------------------------
__global__ void transpose_to_bf16(const float* __restrict__ in, __bf16* __restrict__ outT,
                                  int K, int N)
{
    __shared__ float tile[32][33];
    int k0 = blockIdx.x * 32, n0 = blockIdx.y * 32;
    int tr = threadIdx.x >> 5, tc = threadIdx.x & 31;
#pragma unroll
    for (int s = 0; s < 4; ++s)
        tile[tr + 8 * s][tc] = in[(size_t)(k0 + tr + 8 * s) * N + n0 + tc];
    __syncthreads();
#pragma unroll
    for (int s = 0; s < 4; ++s)
        outT[(size_t)(n0 + tr + 8 * s) * K + k0 + tc] = (__bf16)tile[tc][tr + 8 * s];
}

__global__ void transpose_f32(const float* __restrict__ in, float* __restrict__ outT,
                              int K, int N)
{
    __shared__ float tile[32][33];
    int k0 = blockIdx.x * 32, n0 = blockIdx.y * 32;
    int tr = threadIdx.x >> 5, tc = threadIdx.x & 31;
#pragma unroll
    for (int s = 0; s < 4; ++s)
        tile[tr + 8 * s][tc] = in[(size_t)(k0 + tr + 8 * s) * N + n0 + tc];
    __syncthreads();
#pragma unroll
    for (int s = 0; s < 4; ++s)
        outT[(size_t)(n0 + tr + 8 * s) * K + k0 + tc] = tile[tc][tr + 8 * s];
}

// ---------------------------------------------------------------------------
// bf16 MFMA GEMM (decoder, layout HW-validated R4): C = act(A@B + bias).
// ---------------------------------------------------------------------------
template <bool A_F32, int ACT>
__launch_bounds__(256)
__global__ void gemm_mfma(const void* __restrict__ Ap, const __bf16* __restrict__ BT,
                          const float* __restrict__ bias, void* __restrict__ Cp,
                          int M, int N, int K)
{
    __shared__ __bf16 Asm[128 * 32];
    __shared__ __bf16 Bsm[128 * 32];

    const int t    = threadIdx.x;
    const int m0   = blockIdx.y * 128, n0 = blockIdx.x * 128;
    const int wave = t >> 6, lane = t & 63;
    const int wr   = (wave >> 1) * 64, wc = (wave & 1) * 64;
    const int quad = lane >> 4, l16 = lane & 15;
    const int sr   = t >> 1, sh = t & 1;

    floatx4 acc[4][4];
#pragma unroll
    for (int i = 0; i < 4; ++i)
#pragma unroll
        for (int j = 0; j < 4; ++j) acc[i][j] = (floatx4){0.f, 0.f, 0.f, 0.f};

    for (int k0 = 0; k0 < K; k0 += 32) {
        if (A_F32) {
            const float* src = (const float*)Ap + (size_t)(m0 + sr) * K + k0 + sh * 16;
            __bf16 tmp[16];
#pragma unroll
            for (int q = 0; q < 4; ++q) {
                float4 v = *(const float4*)(src + q * 4);
                tmp[q * 4 + 0] = (__bf16)v.x; tmp[q * 4 + 1] = (__bf16)v.y;
                tmp[q * 4 + 2] = (__bf16)v.z; tmp[q * 4 + 3] = (__bf16)v.w;
            }
            *(bf16x8*)&Asm[sr * 32 + sh * 16 + 0] = *(bf16x8*)&tmp[0];
            *(bf16x8*)&Asm[sr * 32 + sh * 16 + 8] = *(bf16x8*)&tmp[8];
        } else {
            const __bf16* src = (const __bf16*)Ap + (size_t)(m0 + sr) * K + k0 + sh * 16;
            *(uint4*)&Asm[sr * 32 + sh * 16] = *(const uint4*)src;
            *(uint4*)&Asm[sr * 32 + sh * 16 + 8] = *(const uint4*)(src + 8);
        }
        {
            const __bf16* src = BT + (size_t)(n0 + sr) * K + k0 + sh * 16;
            *(uint4*)&Bsm[sr * 32 + sh * 16] = *(const uint4*)src;
            *(uint4*)&Bsm[sr * 32 + sh * 16 + 8] = *(const uint4*)(src + 8);
        }
        __syncthreads();
        bf16x8 af[4], bfr[4];
#pragma unroll
        for (int i = 0; i < 4; ++i)
            af[i] = *(const bf16x8*)&Asm[(wr + i * 16 + l16) * 32 + quad * 8];
#pragma unroll
        for (int j = 0; j < 4; ++j)
            bfr[j] = *(const bf16x8*)&Bsm[(wc + j * 16 + l16) * 32 + quad * 8];
#pragma unroll
        for (int i = 0; i < 4; ++i)
#pragma unroll
            for (int j = 0; j < 4; ++j)
                acc[i][j] = __builtin_amdgcn_mfma_f32_16x16x32_bf16(af[i], bfr[j], acc[i][j], 0, 0, 0);
        __syncthreads();
    }

#pragma unroll
    for (int i = 0; i < 4; ++i)
#pragma unroll
        for (int j = 0; j < 4; ++j) {
            int col = n0 + wc + j * 16 + l16;
            float b = bias[col];
#pragma unroll
            for (int r = 0; r < 4; ++r) {
                int row = m0 + wr + i * 16 + quad * 4 + r;
                float v = acc[i][j][r] + b;
                if (ACT == 1) {
                    v = fmaxf(v, 0.f);
                    ((__bf16*)Cp)[(size_t)row * N + col] = (__bf16)v;
                } else {
                    v = 1.f / (1.f + __expf(-v));
                    ((float*)Cp)[(size_t)row * N + col] = v;
                }
            }
        }
}

// ---------------------------------------------------------------------------
extern "C" void kernel_launch(void* const* d_in, const int* in_sizes, int n_in,
                              void* d_out, int out_size, void* d_ws, size_t ws_size,
                              hipStream_t stream)
{
    const float* x  = (const float*)d_in[0];
    const float* W1 = (const float*)d_in[1];
    const float* b1 = (const float*)d_in[2];
    const float* W2 = (const float*)d_in[3];
    const float* b2 = (const float*)d_in[4];
    const float* cb = (const float*)d_in[5];
    const float* W3 = (const float*)d_in[6];
    const float* b3 = (const float*)d_in[7];
    const float* W4 = (const float*)d_in[8];
    const float* b4 = (const float*)d_in[9];
    float* out = (float*)d_out;

    char* ws = (char*)d_ws;
    // h fp32 (128MB) live G1->G2 only; h2b bf16 (decoder) aliases at +16MB.
    // The dead-h region [0,16MB) hosts the post-G2 score-path scratch:
    //   zh fp16 [16384][128] @ +0        (4 MB)
    //   ch fp16 [8192][128]  @ +4 MB     (2 MB)
    //   gbestA               @ +6 MB     (128 KB)
    //   cand list            @ +8 MB     (8 MB, ends exactly at h2b)
    float*  h    = (float*)(ws);
    __bf16* h2b  = (__bf16*)(ws + 16777216ull);       // 64 MB
    float*  z32  = (float*)(ws + 134217728ull);       //  8 MB
    float*  zq   = (float*)(ws + 142606336ull);       //  8 MB
    float*  W1t  = (float*)(ws + 142606336ull);       //  8 MB (alias of zq)
    float*  nz32 = (float*)(ws + 150994944ull);       // 64 KB
    float*  cn32 = (float*)(ws + 151060480ull);       // 32 KB
    unsigned long long* gbest = (unsigned long long*)(ws + 151093248ull); // 128 KB
    double* acc  = (double*)(ws + 151224320ull);      // 8 B (4KB pad)
    float*  cnmax   = (float*)(ws + 151224328ull);    // 4 B (in acc pad)
    unsigned* listCnt = (unsigned*)(ws + 151224332ull); // 4 B (in acc pad)
    __bf16* W3t  = (__bf16*)(ws + 151228416ull);      // 512 KB [2048][128]
    __bf16* W4t  = (__bf16*)(ws + 151752704ull);      //   4 MB [1024][2048]
    float*  W2t  = (float*)(ws + 155947008ull);       //   1 MB [128][2048]

    _Float16* zh  = (_Float16*)(ws);                  // dead-h region (post-G2)
    _Float16* chh = (_Float16*)(ws + 4194304ull);
    unsigned long long* gbestA = (unsigned long long*)(ws + 6291456ull);
    unsigned* list = (unsigned*)(ws + 8388608ull);

    init_scalars<<<1, 64, 0, stream>>>(acc, listCnt);
    init_gbest<<<B_ / 256, 256, 0, stream>>>(gbest);
    rownorm_kernel<<<KCB / 4, 256, 0, stream>>>(cb, cn32);
    cnmax_kernel<<<1, 256, 0, stream>>>(cn32, cnmax);
    transpose_to_bf16<<<dim3(DDIM / 32, HID / 32), 256, 0, stream>>>(W3, W3t, DDIM, HID);
    transpose_to_bf16<<<dim3(HID / 32, INDIM / 32), 256, 0, stream>>>(W4, W4t, HID, INDIM);
    transpose_f32<<<dim3(INDIM / 32, HID / 32), 256, 0, stream>>>(W1, W1t, INDIM, HID);
    transpose_f32<<<dim3(HID / 32, DDIM / 32), 256, 0, stream>>>(W2, W2t, HID, DDIM);

    // h = relu(fl32(x@W1 + b1)), f64 MFMA + gll   [16384,1024]x[1024,2048]
    gemm_f64_gll<1><<<dim3(HID / 64, B_ / 128), 256, 0, stream>>>(
        x, W1t, b1, h, B_, HID, INDIM);
    // z32 = fl32(h@W2 + b2), f64 MFMA + gll       [16384,2048]x[2048,128]
    gemm_f64_gll<0><<<dim3(DDIM / 64, B_ / 128), 256, 0, stream>>>(
        h, W2t, b2, z32, B_, DDIM, HID);
    // nz32 = fl32(sum fl32(z^2))
    rownorm_kernel<<<B_ / 4, 256, 0, stream>>>(z32, nz32);

    // --- fast score path: fp16 sweeps + exact refine (bit-identical gbest) ---
    init_gbest<<<B_ / 256, 256, 0, stream>>>(gbestA);
    cvt_half<<<(B_ * DDIM / 8) / 256, 256, 0, stream>>>(z32, zh, 1.0f, B_ * DDIM / 8);
    cvt_half<<<(KCB * DDIM / 8) / 256, 256, 0, stream>>>(cb, chh, 4096.0f, KCB * DDIM / 8);
    score_sweep<0><<<dim3(KCB / 128, B_ / 128), 256, 0, stream>>>(
        zh, chh, nz32, cn32, gbestA, cnmax, listCnt, list);
    score_sweep<1><<<dim3(KCB / 128, B_ / 128), 256, 0, stream>>>(
        zh, chh, nz32, cn32, gbestA, cnmax, listCnt, list);
    refine_kernel<<<1024, 256, 0, stream>>>(z32, cb, nz32, cn32, listCnt, list, gbest);

    // z_q gather + commitment loss
    gather_zq_loss<<<B_ / 4, 256, 0, stream>>>(z32, cb, gbest, zq, acc);
    // h2 = relu(zq@W3 + b3) -> bf16               [16384,128]x[128,2048]
    gemm_mfma<true, 1><<<dim3(HID / 128, B_ / 128), 256, 0, stream>>>(
        (const void*)zq, W3t, b3, (void*)h2b, B_, HID, DDIM);
    // recon = sigmoid(h2@W4 + b4) -> fp32 out     [16384,2048]x[2048,1024]
    gemm_mfma<false, 2><<<dim3(INDIM / 128, B_ / 128), 256, 0, stream>>>(
        (const void*)h2b, W4t, b4, (void*)out, B_, INDIM, HID);

    finalize_kernel<<<B_ / 256, 256, 0, stream>>>(gbest, acc, out);
}

// Round 3
// 1523.371 us; speedup vs baseline: 1.6520x; 1.5762x over previous
//
#include <hip/hip_runtime.h>
#include <hip/hip_bf16.h>

// VQ-VAE forward. R10 = R9 with the cvt_pkrtz return-type fix (__fp16x2).
// Encoder G1 (x@W1): 3-pass fp16-split MFMA GEMM (exact 2-way fp16
// decomposition, fp32 accum chunk-promoted to f64) -- h to ~3e-7 abs.
// G2 (h@W2 -> z) stays f64-MFMA (argmin anchor). Score/argmin: fp16-MFMA
// sweeps + exact f64 refine (R8). Decoder: bf16 MFMA.
// Outputs (flat fp32): recon[16384*1024], loss[1], indices-as-float[16384].

#define B_    16384
#define INDIM 1024
#define HID   2048
#define KCB   8192
#define DDIM  128

#define CAND_CAP 2000000u

typedef __bf16    bf16x8   __attribute__((ext_vector_type(8)));
typedef float     floatx4  __attribute__((ext_vector_type(4)));
typedef double    doublex4 __attribute__((ext_vector_type(4)));
typedef _Float16  half8    __attribute__((ext_vector_type(8)));
typedef __fp16    fp16x2   __attribute__((ext_vector_type(2)));

// split scales (exact powers of two)
#define XS 4096.0f              // 2^12 on x
#define WS 8192.0f              // 2^13 on W1
#define SCALE_INV 2.9802322387695312e-08  // 2^-25

__device__ __forceinline__ unsigned long long pack_key(float d, int code)
{
    unsigned int u = __float_as_uint(d);
    u = (u & 0x80000000u) ? ~u : (u | 0x80000000u);   // total order matching float <
    return ((unsigned long long)u << 32) | (unsigned int)code;
}

__device__ __forceinline__ float unpack_d(unsigned long long key)
{
    unsigned int u = (unsigned int)(key >> 32);
    u = (u & 0x80000000u) ? (u ^ 0x80000000u) : ~u;
    return __uint_as_float(u);
}

// Async global->LDS, 16 B per lane. LDS dest: wave-uniform base + lane*16.
__device__ __forceinline__ void gll16(const float* g, float* l)
{
    __builtin_amdgcn_global_load_lds(
        (const __attribute__((address_space(1))) void*)g,
        (__attribute__((address_space(3))) void*)l, 16, 0, 0);
}

// ---------------------------------------------------------------------------
// fp32-in GEMM, f64 MFMA accumulate, single fp32 rounding (+opt relu).
// Used for G2 (z anchor). BM=128 BN=64 BK=32, 4 waves 2x2.
// ---------------------------------------------------------------------------
template <int ACT>
__launch_bounds__(256)
__global__ void gemm_f64_gll(const float* __restrict__ A, const float* __restrict__ BT,
                             const float* __restrict__ bias, float* __restrict__ Cout,
                             int M, int N, int K)
{
    __shared__ float As[128 * 32];
    __shared__ float Bs[64 * 32];

    const int t    = threadIdx.x;
    const int m0   = blockIdx.y * 128, n0 = blockIdx.x * 64;
    const int wave = t >> 6, lane = t & 63;
    const int wr   = (wave >> 1) * 64, wc = (wave & 1) * 32;
    const int quad = lane >> 4, l16 = lane & 15;
    const int lr   = lane >> 3;                 // row within 8-row staging group
    const int lc   = ((lane & 7) ^ lr) * 4;     // swizzled global col (floats)

    doublex4 p0 = {0.0, 0.0, 0.0, 0.0};
    doublex4 prow = __builtin_amdgcn_mfma_f64_16x16x4f64((double)l16, 1.0, p0, 0, 0, 0);
    doublex4 pcol = __builtin_amdgcn_mfma_f64_16x16x4f64(1.0, (double)l16, p0, 0, 0, 0);
    int rowmap[4], colmap[4];
#pragma unroll
    for (int r = 0; r < 4; ++r) {
        rowmap[r] = (int)(prow[r] * 0.25);
        colmap[r] = (int)(pcol[r] * 0.25);
    }

    doublex4 acc[4][2];
#pragma unroll
    for (int i = 0; i < 4; ++i)
#pragma unroll
        for (int j = 0; j < 2; ++j) acc[i][j] = (doublex4){0.0, 0.0, 0.0, 0.0};

    for (int k0 = 0; k0 < K; k0 += 32) {
        __syncthreads();
#pragma unroll
        for (int s = 0; s < 4; ++s) {          // A: wave covers 32 rows
            int r = wave * 32 + s * 8;
            gll16(A + (size_t)(m0 + r + lr) * K + k0 + lc, &As[r * 32]);
        }
#pragma unroll
        for (int s = 0; s < 2; ++s) {          // B: wave covers 16 rows
            int r = wave * 16 + s * 8;
            gll16(BT + (size_t)(n0 + r + lr) * K + k0 + lc, &Bs[r * 32]);
        }
        __syncthreads();
#pragma unroll
        for (int ks = 0; ks < 32; ks += 4) {
            const int cbase = (ks >> 2) ^ (l16 & 7);   // swizzled chunk
            double a[4], b[2];
#pragma unroll
            for (int i = 0; i < 4; ++i)
                a[i] = (double)As[(wr + i * 16 + l16) * 32 + cbase * 4 + quad];
#pragma unroll
            for (int j = 0; j < 2; ++j)
                b[j] = (double)Bs[(wc + j * 16 + l16) * 32 + cbase * 4 + quad];
#pragma unroll
            for (int i = 0; i < 4; ++i)
#pragma unroll
                for (int j = 0; j < 2; ++j)
                    acc[i][j] = __builtin_amdgcn_mfma_f64_16x16x4f64(a[i], b[j], acc[i][j], 0, 0, 0);
        }
    }

#pragma unroll
    for (int i = 0; i < 4; ++i)
#pragma unroll
        for (int j = 0; j < 2; ++j)
#pragma unroll
            for (int r = 0; r < 4; ++r) {
                int row = m0 + wr + i * 16 + rowmap[r];
                int col = n0 + wc + j * 16 + colmap[r];
                float f = (float)(acc[i][j][r] + (double)bias[col]);  // single fp32 round
                if (ACT == 1) f = fmaxf(f, 0.f);
                Cout[(size_t)row * N + col] = f;
            }
}

// ---------------------------------------------------------------------------
// G1: fp32 GEMM emulated by 2-way fp16 splits + fp16 MFMA (3 passes) with
// f64 chunk-promoted accumulation (chunk K=128). A [M][K] fp32 staged
// (XOR-swizzled fp32 LDS via gll16), split in-register with v_cvt_pkrtz.
// B pre-split offline: Bs_g [N][2*K] halves, per 32-k tile 8 logical 16B
// chunks [plane(2)][kchunk(4)], LDS slot = chunk ^ (row&7) via pre-swizzled
// global source. BM=128 BN=64 BK=32, 4 waves 2x2, wave tile 64x32.
// Error <= ~3e-7 abs on pre-activation (below jax fp32 ref's own noise).
// ---------------------------------------------------------------------------
__launch_bounds__(256)
__global__ void gemm_split_f16(const float* __restrict__ A, const _Float16* __restrict__ Bs_g,
                               const float* __restrict__ bias, float* __restrict__ Cout,
                               int M, int N, int K)
{
    __shared__ float    As[128 * 32];       // [row][8 slots][4 floats]
    __shared__ _Float16 Bsh[64 * 64];       // [row][8 slots][8 halves]

    const int t    = threadIdx.x;
    const int m0   = blockIdx.y * 128, n0 = blockIdx.x * 64;
    const int wave = t >> 6, lane = t & 63;
    const int wr   = (wave >> 1) * 64, wc = (wave & 1) * 32;
    const int quad = lane >> 4, l16 = lane & 15;
    const int lr   = lane >> 3;                 // A-staging row in 8-row group
    const int lcA  = ((lane & 7) ^ lr) * 4;     // A swizzled global col (floats)
    const int slB  = lane & 7;                  // B-staging slot
    const int lrB  = lane >> 3;                 // B-staging row in 8-row group

    floatx4  accf[4][2];
    doublex4 accd[4][2];
#pragma unroll
    for (int i = 0; i < 4; ++i)
#pragma unroll
        for (int j = 0; j < 2; ++j) {
            accf[i][j] = (floatx4){0.f, 0.f, 0.f, 0.f};
            accd[i][j] = (doublex4){0.0, 0.0, 0.0, 0.0};
        }

    const int NKT = K >> 5;
    for (int kt = 0; kt < NKT; ++kt) {
        const int k0 = kt << 5;
        __syncthreads();
#pragma unroll
        for (int s = 0; s < 4; ++s) {          // A: wave covers 32 rows
            int r = wave * 32 + s * 8;
            gll16(A + (size_t)(m0 + r + lr) * K + k0 + lcA, &As[r * 32]);
        }
#pragma unroll
        for (int s = 0; s < 2; ++s) {          // B: wave covers 16 rows (8/gll)
            int rb = wave * 16 + s * 8 + lrB;
            int ccs = slB ^ (lrB & 7);         // pre-swizzled logical chunk
            gll16((const float*)(Bs_g + (size_t)(n0 + rb) * (2 * K) + kt * 64 + ccs * 8),
                  (float*)&Bsh[(wave * 16 + s * 8) * 64]);
        }
        __syncthreads();

        // --- A fragments: read 8 fp32, split to two fp16 planes ---
        half8 a1[4], a2[4];
#pragma unroll
        for (int i = 0; i < 4; ++i) {
            const int row = wr + i * 16 + l16;
            const int s0  = (2 * quad) ^ (row & 7);
            const int s1  = (2 * quad + 1) ^ (row & 7);
            floatx4 f0 = *(const floatx4*)&As[row * 32 + s0 * 4];
            floatx4 f1 = *(const floatx4*)&As[row * 32 + s1 * 4];
            union { half8 v; fp16x2 h[4]; } u1, u2;
            float sv[8];
#pragma unroll
            for (int q = 0; q < 4; ++q) sv[q] = f0[q] * XS;
#pragma unroll
            for (int q = 0; q < 4; ++q) sv[4 + q] = f1[q] * XS;
#pragma unroll
            for (int q = 0; q < 4; ++q) {
                fp16x2 hi = __builtin_amdgcn_cvt_pkrtz(sv[2 * q], sv[2 * q + 1]);
                u1.h[q] = hi;
                float r0 = sv[2 * q] - (float)hi[0];
                float r1 = sv[2 * q + 1] - (float)hi[1];
                u2.h[q] = __builtin_amdgcn_cvt_pkrtz(r0, r1);
            }
            a1[i] = u1.v; a2[i] = u2.v;
        }
        // --- B fragments: two pre-split planes straight from LDS ---
        half8 b1[2], b2[2];
#pragma unroll
        for (int j = 0; j < 2; ++j) {
            const int row = wc + j * 16 + l16;
            b1[j] = *(const half8*)&Bsh[row * 64 + ((0 + quad) ^ (row & 7)) * 8];
            b2[j] = *(const half8*)&Bsh[row * 64 + ((4 + quad) ^ (row & 7)) * 8];
        }
        // --- 3 passes: a1b1, a1b2, a2b1 (a2b2 ~2^-22 rel, dropped) ---
#pragma unroll
        for (int i = 0; i < 4; ++i)
#pragma unroll
            for (int j = 0; j < 2; ++j)
                accf[i][j] = __builtin_amdgcn_mfma_f32_16x16x32_f16(a1[i], b1[j], accf[i][j], 0, 0, 0);
#pragma unroll
        for (int i = 0; i < 4; ++i)
#pragma unroll
            for (int j = 0; j < 2; ++j)
                accf[i][j] = __builtin_amdgcn_mfma_f32_16x16x32_f16(a1[i], b2[j], accf[i][j], 0, 0, 0);
#pragma unroll
        for (int i = 0; i < 4; ++i)
#pragma unroll
            for (int j = 0; j < 2; ++j)
                accf[i][j] = __builtin_amdgcn_mfma_f32_16x16x32_f16(a2[i], b1[j], accf[i][j], 0, 0, 0);

        if ((kt & 3) == 3) {                   // f64 promote every K=128 chunk
#pragma unroll
            for (int i = 0; i < 4; ++i)
#pragma unroll
                for (int j = 0; j < 2; ++j) {
#pragma unroll
                    for (int r = 0; r < 4; ++r)
                        accd[i][j][r] += (double)accf[i][j][r] * SCALE_INV;
                    accf[i][j] = (floatx4){0.f, 0.f, 0.f, 0.f};
                }
        }
    }
    if (NKT & 3) {                             // tail promote (K%128 != 0)
#pragma unroll
        for (int i = 0; i < 4; ++i)
#pragma unroll
            for (int j = 0; j < 2; ++j)
#pragma unroll
                for (int r = 0; r < 4; ++r)
                    accd[i][j][r] += (double)accf[i][j][r] * SCALE_INV;
    }

#pragma unroll
    for (int i = 0; i < 4; ++i)
#pragma unroll
        for (int j = 0; j < 2; ++j)
#pragma unroll
            for (int r = 0; r < 4; ++r) {
                int row = m0 + wr + i * 16 + quad * 4 + r;
                int col = n0 + wc + j * 16 + l16;
                float f = (float)(accd[i][j][r] + (double)bias[col]);
                f = fmaxf(f, 0.f);             // relu (G1 only)
                Cout[(size_t)row * N + col] = f;
            }
}

// W1 [K][N] fp32 -> Bs_g [N][2*K] halves: per 32-k tile, chunks
// [plane p(0..1)][kchunk c(0..3)][8 halves], logical (unswizzled) order.
__global__ void transpose_split_f16(const float* __restrict__ in, _Float16* __restrict__ outS,
                                    int K, int N)
{
    __shared__ float tile[32][33];
    int k0 = blockIdx.x * 32, n0 = blockIdx.y * 32;
    int tr = threadIdx.x >> 5, tc = threadIdx.x & 31;
#pragma unroll
    for (int s = 0; s < 4; ++s)
        tile[tr + 8 * s][tc] = in[(size_t)(k0 + tr + 8 * s) * N + n0 + tc];
    __syncthreads();
#pragma unroll
    for (int s = 0; s < 4; ++s) {
        int n = n0 + tr + 8 * s;
        int k = k0 + tc;
        float w = tile[tc][tr + 8 * s] * WS;
        _Float16 p0 = (_Float16)w;
        float r = w - (float)p0;
        _Float16 p1 = (_Float16)r;
        size_t base = (size_t)n * (2 * K) + (size_t)(k >> 5) * 64 + (k & 31);
        outS[base]      = p0;
        outS[base + 32] = p1;
    }
}

// ---------------------------------------------------------------------------
// rownorm32[k] = fl32( sum_fp64( fl32(row[k][d]^2) ) ). One wave per row.
// ---------------------------------------------------------------------------
__global__ void rownorm_kernel(const float* __restrict__ M, float* __restrict__ nrm)
{
    int k = blockIdx.x * 4 + (threadIdx.x >> 6);
    int lane = threadIdx.x & 63;
    float2 c = *(const float2*)(M + (size_t)k * DDIM + lane * 2);
    float q0 = c.x * c.x;
    float q1 = c.y * c.y;
    double s = (double)q0 + (double)q1;
#pragma unroll
    for (int off = 32; off > 0; off >>= 1) s += __shfl_down(s, off);
    if (lane == 0) nrm[k] = (float)s;
}

// max over cn32 (one block).
__global__ void cnmax_kernel(const float* __restrict__ cn, float* __restrict__ out)
{
    __shared__ float red[4];
    int t = threadIdx.x;
    float m = 0.f;
    for (int i = t; i < KCB; i += 256) m = fmaxf(m, cn[i]);
#pragma unroll
    for (int off = 32; off > 0; off >>= 1) m = fmaxf(m, __shfl_down(m, off));
    if ((t & 63) == 0) red[t >> 6] = m;
    __syncthreads();
    if (t == 0) out[0] = fmaxf(fmaxf(red[0], red[1]), fmaxf(red[2], red[3]));
}

// fp32 -> fp16 (optionally scaled by an exact power of two), 8 elems/thread.
__global__ void cvt_half(const float* __restrict__ in, _Float16* __restrict__ out,
                         float scale, int n8)
{
    int i = blockIdx.x * 256 + threadIdx.x;
    if (i >= n8) return;
    const float4 a = *(const float4*)(in + (size_t)i * 8);
    const float4 b = *(const float4*)(in + (size_t)i * 8 + 4);
    half8 h;
    h[0] = (_Float16)(a.x * scale); h[1] = (_Float16)(a.y * scale);
    h[2] = (_Float16)(a.z * scale); h[3] = (_Float16)(a.w * scale);
    h[4] = (_Float16)(b.x * scale); h[5] = (_Float16)(b.y * scale);
    h[6] = (_Float16)(b.z * scale); h[7] = (_Float16)(b.w * scale);
    *(half8*)(out + (size_t)i * 8) = h;
}

// ---------------------------------------------------------------------------
// fp16 approximate score sweeps. 128x128 tile, full K=128 staged once.
// EMIT=0: per-row approx min -> gbestA. EMIT=1: emit candidates with
// d_a <= minA + W (rigorous Cauchy-Schwarz window) to the list.
// ---------------------------------------------------------------------------
template <int EMIT>
__launch_bounds__(256)
__global__ void score_sweep(const _Float16* __restrict__ zh, const _Float16* __restrict__ ch,
                            const float* __restrict__ nz32, const float* __restrict__ cn32,
                            unsigned long long* __restrict__ gbestA,
                            const float* __restrict__ cnmaxp,
                            unsigned* __restrict__ listCnt, unsigned* __restrict__ list)
{
    __shared__ __align__(16) _Float16 As[128 * 128];
    __shared__ __align__(16) _Float16 Bs[128 * 128];
    __shared__ unsigned long long best[128];

    const int t    = threadIdx.x;
    const int m0   = blockIdx.y * 128;   // rows
    const int n0   = blockIdx.x * 128;   // codes
    const int wave = t >> 6, lane = t & 63;
    const int wr   = (wave >> 1) * 64, wc = (wave & 1) * 64;
    const int quad = lane >> 4, l16 = lane & 15;

    if (EMIT == 0 && t < 128) best[t] = ~0ull;

    const int srow = lane >> 4;          // row within 4-row group
    const int sc   = lane & 15;          // 16B chunk within row
#pragma unroll
    for (int s = 0; s < 8; ++s) {
        const int rbase = wave * 32 + s * 4;
        const int ra = rbase + srow;
        const int cs = sc ^ ((ra & 7) << 1);   // pre-swizzled SOURCE chunk
        gll16((const float*)(zh + (size_t)(m0 + ra) * 128 + cs * 8),
              (float*)&As[rbase * 128]);
        gll16((const float*)(ch + (size_t)(n0 + ra) * 128 + cs * 8),
              (float*)&Bs[rbase * 128]);
    }
    __syncthreads();   // drains vmcnt

    floatx4 acc[4][4];
#pragma unroll
    for (int i = 0; i < 4; ++i)
#pragma unroll
        for (int j = 0; j < 4; ++j) acc[i][j] = (floatx4){0.f, 0.f, 0.f, 0.f};

#pragma unroll
    for (int ks = 0; ks < 4; ++ks) {
        half8 af[4], bfr[4];
#pragma unroll
        for (int i = 0; i < 4; ++i) {
            const int rl = wr + i * 16 + l16;
            const int cc = (ks * 4 + quad) ^ ((rl & 7) << 1);
            af[i] = *(const half8*)&As[rl * 128 + cc * 8];
        }
#pragma unroll
        for (int j = 0; j < 4; ++j) {
            const int rl = wc + j * 16 + l16;
            const int cc = (ks * 4 + quad) ^ ((rl & 7) << 1);
            bfr[j] = *(const half8*)&Bs[rl * 128 + cc * 8];
        }
#pragma unroll
        for (int i = 0; i < 4; ++i)
#pragma unroll
            for (int j = 0; j < 4; ++j)
                acc[i][j] = __builtin_amdgcn_mfma_f32_16x16x32_f16(af[i], bfr[j], acc[i][j], 0, 0, 0);
    }

    const float cnm = *cnmaxp;
#pragma unroll
    for (int i = 0; i < 4; ++i)
#pragma unroll
        for (int r = 0; r < 4; ++r) {
            const int lrow = wr + i * 16 + quad * 4 + r;
            const int grow = m0 + lrow;
            const float nz = nz32[grow];
            if (EMIT) {
                const float minA = unpack_d(gbestA[grow]);
                const float thr  = minA + 2.4e-3f * sqrtf(nz * cnm) + 6.0e-5f;
#pragma unroll
                for (int j = 0; j < 4; ++j) {
                    const int code = n0 + wc + j * 16 + l16;
                    float s = acc[i][j][r] * (1.0f / 4096.0f);
                    float d = (nz - 2.0f * s) + cn32[code];
                    if (d <= thr) {
                        unsigned idx = atomicAdd(listCnt, 1u);
                        if (idx < CAND_CAP)
                            list[idx] = ((unsigned)grow << 13) | (unsigned)code;
                    }
                }
            } else {
                float bd = 3.4e38f; int bc = 0x7fffffff;
#pragma unroll
                for (int j = 0; j < 4; ++j) {
                    const int code = n0 + wc + j * 16 + l16;
                    float s = acc[i][j][r] * (1.0f / 4096.0f);
                    float d = (nz - 2.0f * s) + cn32[code];
                    if (d < bd || (d == bd && code < bc)) { bd = d; bc = code; }
                }
                atomicMin(&best[lrow], pack_key(bd, bc));
            }
        }

    if (EMIT == 0) {
        __syncthreads();
        if (t < 128) atomicMin(&gbestA[m0 + t], best[t]);
    }
}

// Exact refine: one wave per candidate pair. Reproduces the exact semantics:
// s32 = fl32(f64 sum(z*c)); d = fl32(fl32(nz-2*s32)+cn); packed min.
__launch_bounds__(256)
__global__ void refine_kernel(const float* __restrict__ z, const float* __restrict__ cb,
                              const float* __restrict__ nz32, const float* __restrict__ cn32,
                              const unsigned* __restrict__ listCnt,
                              const unsigned* __restrict__ list,
                              unsigned long long* __restrict__ gbest)
{
    unsigned cnt = *listCnt;
    if (cnt > CAND_CAP) cnt = CAND_CAP;
    const int lane = threadIdx.x & 63;
    for (unsigned p = blockIdx.x * 4 + (threadIdx.x >> 6); p < cnt; p += gridDim.x * 4) {
        const unsigned e = list[p];
        const int r = (int)(e >> 13), k = (int)(e & 8191u);
        float2 zv = *(const float2*)(z  + (size_t)r * DDIM + lane * 2);
        float2 cv = *(const float2*)(cb + (size_t)k * DDIM + lane * 2);
        double s = (double)zv.x * (double)cv.x + (double)zv.y * (double)cv.y;
#pragma unroll
        for (int off = 32; off > 0; off >>= 1) s += __shfl_down(s, off);
        if (lane == 0) {
            float s32 = (float)s;
            float d = (nz32[r] - 2.0f * s32) + cn32[k];
            atomicMin(&gbest[r], pack_key(d, k));
        }
    }
}

__global__ void init_gbest(unsigned long long* __restrict__ g)
{
    g[blockIdx.x * 256 + threadIdx.x] = ~0ull;
}

// Gather z_q = codebook[idx] (fp32) and accumulate sum((z_q - z32)^2) in fp64.
__global__ void gather_zq_loss(const float* __restrict__ z, const float* __restrict__ cb,
                               const unsigned long long* __restrict__ gbest,
                               float* __restrict__ zq, double* __restrict__ acc)
{
    int r = blockIdx.x * 4 + (threadIdx.x >> 6);
    int lane = threadIdx.x & 63;
    int k = (int)(gbest[r] & 0xffffffffull);
    float2 zv = *(const float2*)(z  + (size_t)r * DDIM + lane * 2);
    float2 cv = *(const float2*)(cb + (size_t)k * DDIM + lane * 2);
    *(float2*)(zq + (size_t)r * DDIM + lane * 2) = cv;
    double dx = (double)cv.x - (double)zv.x, dy = (double)cv.y - (double)zv.y;
    double s = dx * dx + dy * dy;
#pragma unroll
    for (int off = 32; off > 0; off >>= 1) s += __shfl_down(s, off);
    if (lane == 0) atomicAdd(acc, s);
}

__global__ void init_scalars(double* acc, unsigned* cnt)
{
    if (threadIdx.x == 0 && blockIdx.x == 0) { *acc = 0.0; *cnt = 0u; }
}

__global__ void finalize_kernel(const unsigned long long* __restrict__ gbest,
                                const double* __restrict__ acc, float* __restrict__ out)
{
    int tid = blockIdx.x * 256 + threadIdx.x;
    if (tid < B_) out[16777217 + tid] = (float)(int)(gbest[tid] & 0xffffffffull);
    if (tid == 0) out[16777216] = (float)((*acc) * 1.25 / (double)(B_ * DDIM));
}

// ---------------------------------------------------------------------------
// One-time weight transposes: fp32 [K][N] -> bf16/fp32 [N][K].
// ---------------------------------------------------------------------------
__global__ void transpose_to_bf16(const float* __restrict__ in, __bf16* __restrict__ outT,
                                  int K, int N)
{
    __shared__ float tile[32][33];
    int k0 = blockIdx.x * 32, n0 = blockIdx.y * 32;
    int tr = threadIdx.x >> 5, tc = threadIdx.x & 31;
#pragma unroll
    for (int s = 0; s < 4; ++s)
        tile[tr + 8 * s][tc] = in[(size_t)(k0 + tr + 8 * s) * N + n0 + tc];
    __syncthreads();
#pragma unroll
    for (int s = 0; s < 4; ++s)
        outT[(size_t)(n0 + tr + 8 * s) * K + k0 + tc] = (__bf16)tile[tc][tr + 8 * s];
}

__global__ void transpose_f32(const float* __restrict__ in, float* __restrict__ outT,
                              int K, int N)
{
    __shared__ float tile[32][33];
    int k0 = blockIdx.x * 32, n0 = blockIdx.y * 32;
    int tr = threadIdx.x >> 5, tc = threadIdx.x & 31;
#pragma unroll
    for (int s = 0; s < 4; ++s)
        tile[tr + 8 * s][tc] = in[(size_t)(k0 + tr + 8 * s) * N + n0 + tc];
    __syncthreads();
#pragma unroll
    for (int s = 0; s < 4; ++s)
        outT[(size_t)(n0 + tr + 8 * s) * K + k0 + tc] = tile[tc][tr + 8 * s];
}

// ---------------------------------------------------------------------------
// bf16 MFMA GEMM (decoder, layout HW-validated R4): C = act(A@B + bias).
// ---------------------------------------------------------------------------
template <bool A_F32, int ACT>
__launch_bounds__(256)
__global__ void gemm_mfma(const void* __restrict__ Ap, const __bf16* __restrict__ BT,
                          const float* __restrict__ bias, void* __restrict__ Cp,
                          int M, int N, int K)
{
    __shared__ __bf16 Asm[128 * 32];
    __shared__ __bf16 Bsm[128 * 32];

    const int t    = threadIdx.x;
    const int m0   = blockIdx.y * 128, n0 = blockIdx.x * 128;
    const int wave = t >> 6, lane = t & 63;
    const int wr   = (wave >> 1) * 64, wc = (wave & 1) * 64;
    const int quad = lane >> 4, l16 = lane & 15;
    const int sr   = t >> 1, sh = t & 1;

    floatx4 acc[4][4];
#pragma unroll
    for (int i = 0; i < 4; ++i)
#pragma unroll
        for (int j = 0; j < 4; ++j) acc[i][j] = (floatx4){0.f, 0.f, 0.f, 0.f};

    for (int k0 = 0; k0 < K; k0 += 32) {
        if (A_F32) {
            const float* src = (const float*)Ap + (size_t)(m0 + sr) * K + k0 + sh * 16;
            __bf16 tmp[16];
#pragma unroll
            for (int q = 0; q < 4; ++q) {
                float4 v = *(const float4*)(src + q * 4);
                tmp[q * 4 + 0] = (__bf16)v.x; tmp[q * 4 + 1] = (__bf16)v.y;
                tmp[q * 4 + 2] = (__bf16)v.z; tmp[q * 4 + 3] = (__bf16)v.w;
            }
            *(bf16x8*)&Asm[sr * 32 + sh * 16 + 0] = *(bf16x8*)&tmp[0];
            *(bf16x8*)&Asm[sr * 32 + sh * 16 + 8] = *(bf16x8*)&tmp[8];
        } else {
            const __bf16* src = (const __bf16*)Ap + (size_t)(m0 + sr) * K + k0 + sh * 16;
            *(uint4*)&Asm[sr * 32 + sh * 16] = *(const uint4*)src;
            *(uint4*)&Asm[sr * 32 + sh * 16 + 8] = *(const uint4*)(src + 8);
        }
        {
            const __bf16* src = BT + (size_t)(n0 + sr) * K + k0 + sh * 16;
            *(uint4*)&Bsm[sr * 32 + sh * 16] = *(const uint4*)src;
            *(uint4*)&Bsm[sr * 32 + sh * 16 + 8] = *(const uint4*)(src + 8);
        }
        __syncthreads();
        bf16x8 af[4], bfr[4];
#pragma unroll
        for (int i = 0; i < 4; ++i)
            af[i] = *(const bf16x8*)&Asm[(wr + i * 16 + l16) * 32 + quad * 8];
#pragma unroll
        for (int j = 0; j < 4; ++j)
            bfr[j] = *(const bf16x8*)&Bsm[(wc + j * 16 + l16) * 32 + quad * 8];
#pragma unroll
        for (int i = 0; i < 4; ++i)
#pragma unroll
            for (int j = 0; j < 4; ++j)
                acc[i][j] = __builtin_amdgcn_mfma_f32_16x16x32_bf16(af[i], bfr[j], acc[i][j], 0, 0, 0);
        __syncthreads();
    }

#pragma unroll
    for (int i = 0; i < 4; ++i)
#pragma unroll
        for (int j = 0; j < 4; ++j) {
            int col = n0 + wc + j * 16 + l16;
            float b = bias[col];
#pragma unroll
            for (int r = 0; r < 4; ++r) {
                int row = m0 + wr + i * 16 + quad * 4 + r;
                float v = acc[i][j][r] + b;
                if (ACT == 1) {
                    v = fmaxf(v, 0.f);
                    ((__bf16*)Cp)[(size_t)row * N + col] = (__bf16)v;
                } else {
                    v = 1.f / (1.f + __expf(-v));
                    ((float*)Cp)[(size_t)row * N + col] = v;
                }
            }
        }
}

// ---------------------------------------------------------------------------
extern "C" void kernel_launch(void* const* d_in, const int* in_sizes, int n_in,
                              void* d_out, int out_size, void* d_ws, size_t ws_size,
                              hipStream_t stream)
{
    const float* x  = (const float*)d_in[0];
    const float* W1 = (const float*)d_in[1];
    const float* b1 = (const float*)d_in[2];
    const float* W2 = (const float*)d_in[3];
    const float* b2 = (const float*)d_in[4];
    const float* cb = (const float*)d_in[5];
    const float* W3 = (const float*)d_in[6];
    const float* b3 = (const float*)d_in[7];
    const float* W4 = (const float*)d_in[8];
    const float* b4 = (const float*)d_in[9];
    float* out = (float*)d_out;

    char* ws = (char*)d_ws;
    // h fp32 (128MB) live G1->G2 only; h2b bf16 (decoder) aliases at +16MB.
    // Dead-h region [0,16MB) hosts post-G2 score scratch (zh/ch/gbestA/list).
    // W1s fp16-split planes (8MB, live only during G1) alias zq.
    float*  h    = (float*)(ws);
    __bf16* h2b  = (__bf16*)(ws + 16777216ull);       // 64 MB
    float*  z32  = (float*)(ws + 134217728ull);       //  8 MB
    float*  zq   = (float*)(ws + 142606336ull);       //  8 MB
    _Float16* W1s = (_Float16*)(ws + 142606336ull);   //  8 MB (alias of zq)
    float*  nz32 = (float*)(ws + 150994944ull);       // 64 KB
    float*  cn32 = (float*)(ws + 151060480ull);       // 32 KB
    unsigned long long* gbest = (unsigned long long*)(ws + 151093248ull); // 128 KB
    double* acc  = (double*)(ws + 151224320ull);      // 8 B (4KB pad)
    float*  cnmax   = (float*)(ws + 151224328ull);    // 4 B (in acc pad)
    unsigned* listCnt = (unsigned*)(ws + 151224332ull); // 4 B (in acc pad)
    __bf16* W3t  = (__bf16*)(ws + 151228416ull);      // 512 KB [2048][128]
    __bf16* W4t  = (__bf16*)(ws + 151752704ull);      //   4 MB [1024][2048]
    float*  W2t  = (float*)(ws + 155947008ull);       //   1 MB [128][2048]

    _Float16* zh  = (_Float16*)(ws);                  // dead-h region (post-G2)
    _Float16* chh = (_Float16*)(ws + 4194304ull);
    unsigned long long* gbestA = (unsigned long long*)(ws + 6291456ull);
    unsigned* list = (unsigned*)(ws + 8388608ull);

    init_scalars<<<1, 64, 0, stream>>>(acc, listCnt);
    init_gbest<<<B_ / 256, 256, 0, stream>>>(gbest);
    rownorm_kernel<<<KCB / 4, 256, 0, stream>>>(cb, cn32);
    cnmax_kernel<<<1, 256, 0, stream>>>(cn32, cnmax);
    transpose_to_bf16<<<dim3(DDIM / 32, HID / 32), 256, 0, stream>>>(W3, W3t, DDIM, HID);
    transpose_to_bf16<<<dim3(HID / 32, INDIM / 32), 256, 0, stream>>>(W4, W4t, HID, INDIM);
    transpose_split_f16<<<dim3(INDIM / 32, HID / 32), 256, 0, stream>>>(W1, W1s, INDIM, HID);
    transpose_f32<<<dim3(HID / 32, DDIM / 32), 256, 0, stream>>>(W2, W2t, HID, DDIM);

    // h = relu(x@W1 + b1), fp16-split 3-pass MFMA  [16384,1024]x[1024,2048]
    gemm_split_f16<<<dim3(HID / 64, B_ / 128), 256, 0, stream>>>(
        x, W1s, b1, h, B_, HID, INDIM);
    // z32 = fl32(h@W2 + b2), f64 MFMA + gll       [16384,2048]x[2048,128]
    gemm_f64_gll<0><<<dim3(DDIM / 64, B_ / 128), 256, 0, stream>>>(
        h, W2t, b2, z32, B_, DDIM, HID);
    // nz32 = fl32(sum fl32(z^2))
    rownorm_kernel<<<B_ / 4, 256, 0, stream>>>(z32, nz32);

    // --- fast score path: fp16 sweeps + exact refine (bit-identical gbest) ---
    init_gbest<<<B_ / 256, 256, 0, stream>>>(gbestA);
    cvt_half<<<(B_ * DDIM / 8) / 256, 256, 0, stream>>>(z32, zh, 1.0f, B_ * DDIM / 8);
    cvt_half<<<(KCB * DDIM / 8) / 256, 256, 0, stream>>>(cb, chh, 4096.0f, KCB * DDIM / 8);
    score_sweep<0><<<dim3(KCB / 128, B_ / 128), 256, 0, stream>>>(
        zh, chh, nz32, cn32, gbestA, cnmax, listCnt, list);
    score_sweep<1><<<dim3(KCB / 128, B_ / 128), 256, 0, stream>>>(
        zh, chh, nz32, cn32, gbestA, cnmax, listCnt, list);
    refine_kernel<<<1024, 256, 0, stream>>>(z32, cb, nz32, cn32, listCnt, list, gbest);

    // z_q gather + commitment loss
    gather_zq_loss<<<B_ / 4, 256, 0, stream>>>(z32, cb, gbest, zq, acc);
    // h2 = relu(zq@W3 + b3) -> bf16               [16384,128]x[128,2048]
    gemm_mfma<true, 1><<<dim3(HID / 128, B_ / 128), 256, 0, stream>>>(
        (const void*)zq, W3t, b3, (void*)h2b, B_, HID, DDIM);
    // recon = sigmoid(h2@W4 + b4) -> fp32 out     [16384,2048]x[2048,1024]
    gemm_mfma<false, 2><<<dim3(INDIM / 128, B_ / 128), 256, 0, stream>>>(
        (const void*)h2b, W4t, b4, (void*)out, B_, INDIM, HID);

    finalize_kernel<<<B_ / 256, 256, 0, stream>>>(gbest, acc, out);
}

// Round 4
// 1322.919 us; speedup vs baseline: 1.9023x; 1.1515x over previous
//
#include <hip/hip_runtime.h>
#include <hip/hip_bf16.h>

// VQ-VAE forward. R11: G1 = pure 3-pass fp16-split GEMM with BOTH operands
// pre-split offline (bit-identical h to R10; removes the in-loop cvt VALU
// chain that held G1 at 48% VALUBusy / 23% MfmaUtil). G2 = same split-fp16
// GEMM (in-register A split, cost 12.5% of G1's) replacing f64 MFMA; W2
// pre-split, K=64 promote chunks. Score/argmin: fp16-MFMA sweeps + exact f64
// refine (R8). Decoder: bf16 MFMA. gemm_f64_gll retained as revert path.
// Outputs (flat fp32): recon[16384*1024], loss[1], indices-as-float[16384].

#define B_    16384
#define INDIM 1024
#define HID   2048
#define KCB   8192
#define DDIM  128

#define CAND_CAP 2000000u

typedef __bf16    bf16x8   __attribute__((ext_vector_type(8)));
typedef float     floatx4  __attribute__((ext_vector_type(4)));
typedef double    doublex4 __attribute__((ext_vector_type(4)));
typedef _Float16  half8    __attribute__((ext_vector_type(8)));
typedef __fp16    fp16x2   __attribute__((ext_vector_type(2)));

// split scales (exact powers of two)
#define XS 4096.0f              // 2^12 on A (x or h)
#define WS 8192.0f              // 2^13 on W
#define SCALE_INV 2.9802322387695312e-08  // 2^-25

__device__ __forceinline__ unsigned long long pack_key(float d, int code)
{
    unsigned int u = __float_as_uint(d);
    u = (u & 0x80000000u) ? ~u : (u | 0x80000000u);   // total order matching float <
    return ((unsigned long long)u << 32) | (unsigned int)code;
}

__device__ __forceinline__ float unpack_d(unsigned long long key)
{
    unsigned int u = (unsigned int)(key >> 32);
    u = (u & 0x80000000u) ? (u ^ 0x80000000u) : ~u;
    return __uint_as_float(u);
}

// Async global->LDS, 16 B per lane. LDS dest: wave-uniform base + lane*16.
__device__ __forceinline__ void gll16(const float* g, float* l)
{
    __builtin_amdgcn_global_load_lds(
        (const __attribute__((address_space(1))) void*)g,
        (__attribute__((address_space(3))) void*)l, 16, 0, 0);
}

// ---------------------------------------------------------------------------
// fp32-in GEMM, f64 MFMA accumulate (revert path, not launched).
// ---------------------------------------------------------------------------
template <int ACT>
__launch_bounds__(256)
__global__ void gemm_f64_gll(const float* __restrict__ A, const float* __restrict__ BT,
                             const float* __restrict__ bias, float* __restrict__ Cout,
                             int M, int N, int K)
{
    __shared__ float As[128 * 32];
    __shared__ float Bs[64 * 32];

    const int t    = threadIdx.x;
    const int m0   = blockIdx.y * 128, n0 = blockIdx.x * 64;
    const int wave = t >> 6, lane = t & 63;
    const int wr   = (wave >> 1) * 64, wc = (wave & 1) * 32;
    const int quad = lane >> 4, l16 = lane & 15;
    const int lr   = lane >> 3;
    const int lc   = ((lane & 7) ^ lr) * 4;

    doublex4 p0 = {0.0, 0.0, 0.0, 0.0};
    doublex4 prow = __builtin_amdgcn_mfma_f64_16x16x4f64((double)l16, 1.0, p0, 0, 0, 0);
    doublex4 pcol = __builtin_amdgcn_mfma_f64_16x16x4f64(1.0, (double)l16, p0, 0, 0, 0);
    int rowmap[4], colmap[4];
#pragma unroll
    for (int r = 0; r < 4; ++r) {
        rowmap[r] = (int)(prow[r] * 0.25);
        colmap[r] = (int)(pcol[r] * 0.25);
    }

    doublex4 acc[4][2];
#pragma unroll
    for (int i = 0; i < 4; ++i)
#pragma unroll
        for (int j = 0; j < 2; ++j) acc[i][j] = (doublex4){0.0, 0.0, 0.0, 0.0};

    for (int k0 = 0; k0 < K; k0 += 32) {
        __syncthreads();
#pragma unroll
        for (int s = 0; s < 4; ++s) {
            int r = wave * 32 + s * 8;
            gll16(A + (size_t)(m0 + r + lr) * K + k0 + lc, &As[r * 32]);
        }
#pragma unroll
        for (int s = 0; s < 2; ++s) {
            int r = wave * 16 + s * 8;
            gll16(BT + (size_t)(n0 + r + lr) * K + k0 + lc, &Bs[r * 32]);
        }
        __syncthreads();
#pragma unroll
        for (int ks = 0; ks < 32; ks += 4) {
            const int cbase = (ks >> 2) ^ (l16 & 7);
            double a[4], b[2];
#pragma unroll
            for (int i = 0; i < 4; ++i)
                a[i] = (double)As[(wr + i * 16 + l16) * 32 + cbase * 4 + quad];
#pragma unroll
            for (int j = 0; j < 2; ++j)
                b[j] = (double)Bs[(wc + j * 16 + l16) * 32 + cbase * 4 + quad];
#pragma unroll
            for (int i = 0; i < 4; ++i)
#pragma unroll
                for (int j = 0; j < 2; ++j)
                    acc[i][j] = __builtin_amdgcn_mfma_f64_16x16x4f64(a[i], b[j], acc[i][j], 0, 0, 0);
        }
    }

#pragma unroll
    for (int i = 0; i < 4; ++i)
#pragma unroll
        for (int j = 0; j < 2; ++j)
#pragma unroll
            for (int r = 0; r < 4; ++r) {
                int row = m0 + wr + i * 16 + rowmap[r];
                int col = n0 + wc + j * 16 + colmap[r];
                float f = (float)(acc[i][j][r] + (double)bias[col]);
                if (ACT == 1) f = fmaxf(f, 0.f);
                Cout[(size_t)row * N + col] = f;
            }
}

// ---------------------------------------------------------------------------
// Split-fp16 GEMM, A fp32 with IN-REGISTER split (proven R10 kernel).
// ACT: 1 = relu. PMASK: f64-promote every (PMASK+1) k-tiles.
// ---------------------------------------------------------------------------
template <int ACT, int PMASK>
__launch_bounds__(256)
__global__ void gemm_split_f16(const float* __restrict__ A, const _Float16* __restrict__ Bs_g,
                               const float* __restrict__ bias, float* __restrict__ Cout,
                               int M, int N, int K)
{
    __shared__ float    As[128 * 32];       // [row][8 slots][4 floats]
    __shared__ _Float16 Bsh[64 * 64];       // [row][8 slots][8 halves]

    const int t    = threadIdx.x;
    const int m0   = blockIdx.y * 128, n0 = blockIdx.x * 64;
    const int wave = t >> 6, lane = t & 63;
    const int wr   = (wave >> 1) * 64, wc = (wave & 1) * 32;
    const int quad = lane >> 4, l16 = lane & 15;
    const int lr   = lane >> 3;
    const int lcA  = ((lane & 7) ^ lr) * 4;
    const int slB  = lane & 7;
    const int lrB  = lane >> 3;

    floatx4  accf[4][2];
    doublex4 accd[4][2];
#pragma unroll
    for (int i = 0; i < 4; ++i)
#pragma unroll
        for (int j = 0; j < 2; ++j) {
            accf[i][j] = (floatx4){0.f, 0.f, 0.f, 0.f};
            accd[i][j] = (doublex4){0.0, 0.0, 0.0, 0.0};
        }

    const int NKT = K >> 5;
    for (int kt = 0; kt < NKT; ++kt) {
        const int k0 = kt << 5;
        __syncthreads();
#pragma unroll
        for (int s = 0; s < 4; ++s) {
            int r = wave * 32 + s * 8;
            gll16(A + (size_t)(m0 + r + lr) * K + k0 + lcA, &As[r * 32]);
        }
#pragma unroll
        for (int s = 0; s < 2; ++s) {
            int rb = wave * 16 + s * 8 + lrB;
            int ccs = slB ^ (lrB & 7);
            gll16((const float*)(Bs_g + (size_t)(n0 + rb) * (2 * K) + kt * 64 + ccs * 8),
                  (float*)&Bsh[(wave * 16 + s * 8) * 64]);
        }
        __syncthreads();

        half8 a1[4], a2[4];
#pragma unroll
        for (int i = 0; i < 4; ++i) {
            const int row = wr + i * 16 + l16;
            const int s0  = (2 * quad) ^ (row & 7);
            const int s1  = (2 * quad + 1) ^ (row & 7);
            floatx4 f0 = *(const floatx4*)&As[row * 32 + s0 * 4];
            floatx4 f1 = *(const floatx4*)&As[row * 32 + s1 * 4];
            union { half8 v; fp16x2 h[4]; } u1, u2;
            float sv[8];
#pragma unroll
            for (int q = 0; q < 4; ++q) sv[q] = f0[q] * XS;
#pragma unroll
            for (int q = 0; q < 4; ++q) sv[4 + q] = f1[q] * XS;
#pragma unroll
            for (int q = 0; q < 4; ++q) {
                fp16x2 hi = __builtin_amdgcn_cvt_pkrtz(sv[2 * q], sv[2 * q + 1]);
                u1.h[q] = hi;
                float r0 = sv[2 * q] - (float)hi[0];
                float r1 = sv[2 * q + 1] - (float)hi[1];
                u2.h[q] = __builtin_amdgcn_cvt_pkrtz(r0, r1);
            }
            a1[i] = u1.v; a2[i] = u2.v;
        }
        half8 b1[2], b2[2];
#pragma unroll
        for (int j = 0; j < 2; ++j) {
            const int row = wc + j * 16 + l16;
            b1[j] = *(const half8*)&Bsh[row * 64 + ((0 + quad) ^ (row & 7)) * 8];
            b2[j] = *(const half8*)&Bsh[row * 64 + ((4 + quad) ^ (row & 7)) * 8];
        }
#pragma unroll
        for (int i = 0; i < 4; ++i)
#pragma unroll
            for (int j = 0; j < 2; ++j)
                accf[i][j] = __builtin_amdgcn_mfma_f32_16x16x32_f16(a1[i], b1[j], accf[i][j], 0, 0, 0);
#pragma unroll
        for (int i = 0; i < 4; ++i)
#pragma unroll
            for (int j = 0; j < 2; ++j)
                accf[i][j] = __builtin_amdgcn_mfma_f32_16x16x32_f16(a1[i], b2[j], accf[i][j], 0, 0, 0);
#pragma unroll
        for (int i = 0; i < 4; ++i)
#pragma unroll
            for (int j = 0; j < 2; ++j)
                accf[i][j] = __builtin_amdgcn_mfma_f32_16x16x32_f16(a2[i], b1[j], accf[i][j], 0, 0, 0);

        if ((kt & PMASK) == PMASK) {
#pragma unroll
            for (int i = 0; i < 4; ++i)
#pragma unroll
                for (int j = 0; j < 2; ++j) {
#pragma unroll
                    for (int r = 0; r < 4; ++r)
                        accd[i][j][r] += (double)accf[i][j][r] * SCALE_INV;
                    accf[i][j] = (floatx4){0.f, 0.f, 0.f, 0.f};
                }
        }
    }
    if (NKT & PMASK) {
#pragma unroll
        for (int i = 0; i < 4; ++i)
#pragma unroll
            for (int j = 0; j < 2; ++j)
#pragma unroll
                for (int r = 0; r < 4; ++r)
                    accd[i][j][r] += (double)accf[i][j][r] * SCALE_INV;
    }

#pragma unroll
    for (int i = 0; i < 4; ++i)
#pragma unroll
        for (int j = 0; j < 2; ++j)
#pragma unroll
            for (int r = 0; r < 4; ++r) {
                int row = m0 + wr + i * 16 + quad * 4 + r;
                int col = n0 + wc + j * 16 + l16;
                float f = (float)(accd[i][j][r] + (double)bias[col]);
                if (ACT == 1) f = fmaxf(f, 0.f);
                Cout[(size_t)row * N + col] = f;
            }
}

// ---------------------------------------------------------------------------
// Split-fp16 GEMM, BOTH operands pre-split [rows][2*K] halves (per 32-k tile:
// [plane(2)][kchunk(4)][8 halves]). Zero per-element VALU in the K-loop.
// Staging: 16B chunks to LDS slot chunk^(row&7) via pre-swizzled source.
// BM=128 BN=64 BK=32, 4 waves 2x2. Epilogue: relu + fp32 store (G1).
// ---------------------------------------------------------------------------
__launch_bounds__(256)
__global__ void gemm_split_pre(const _Float16* __restrict__ As_g, const _Float16* __restrict__ Bs_g,
                               const float* __restrict__ bias, float* __restrict__ Cout,
                               int M, int N, int K)
{
    __shared__ _Float16 Ash[128 * 64];      // [row][8 slots][8 halves]
    __shared__ _Float16 Bsh[64 * 64];

    const int t    = threadIdx.x;
    const int m0   = blockIdx.y * 128, n0 = blockIdx.x * 64;
    const int wave = t >> 6, lane = t & 63;
    const int wr   = (wave >> 1) * 64, wc = (wave & 1) * 32;
    const int quad = lane >> 4, l16 = lane & 15;
    const int slB  = lane & 7;                  // staging slot
    const int lrB  = lane >> 3;                 // staging row in 8-row group
    const int ccs  = slB ^ (lrB & 7);           // pre-swizzled source chunk

    floatx4  accf[4][2];
    doublex4 accd[4][2];
#pragma unroll
    for (int i = 0; i < 4; ++i)
#pragma unroll
        for (int j = 0; j < 2; ++j) {
            accf[i][j] = (floatx4){0.f, 0.f, 0.f, 0.f};
            accd[i][j] = (doublex4){0.0, 0.0, 0.0, 0.0};
        }

    const int NKT = K >> 5;
    for (int kt = 0; kt < NKT; ++kt) {
        __syncthreads();
#pragma unroll
        for (int s = 0; s < 4; ++s) {          // A: wave covers 32 rows
            int ra = wave * 32 + s * 8 + lrB;
            gll16((const float*)(As_g + (size_t)(m0 + ra) * (2 * K) + kt * 64 + ccs * 8),
                  (float*)&Ash[(wave * 32 + s * 8) * 64]);
        }
#pragma unroll
        for (int s = 0; s < 2; ++s) {          // B: wave covers 16 rows
            int rb = wave * 16 + s * 8 + lrB;
            gll16((const float*)(Bs_g + (size_t)(n0 + rb) * (2 * K) + kt * 64 + ccs * 8),
                  (float*)&Bsh[(wave * 16 + s * 8) * 64]);
        }
        __syncthreads();

        half8 a1[4], a2[4], b1[2], b2[2];
#pragma unroll
        for (int i = 0; i < 4; ++i) {
            const int row = wr + i * 16 + l16;
            a1[i] = *(const half8*)&Ash[row * 64 + ((0 + quad) ^ (row & 7)) * 8];
            a2[i] = *(const half8*)&Ash[row * 64 + ((4 + quad) ^ (row & 7)) * 8];
        }
#pragma unroll
        for (int j = 0; j < 2; ++j) {
            const int row = wc + j * 16 + l16;
            b1[j] = *(const half8*)&Bsh[row * 64 + ((0 + quad) ^ (row & 7)) * 8];
            b2[j] = *(const half8*)&Bsh[row * 64 + ((4 + quad) ^ (row & 7)) * 8];
        }
#pragma unroll
        for (int i = 0; i < 4; ++i)
#pragma unroll
            for (int j = 0; j < 2; ++j)
                accf[i][j] = __builtin_amdgcn_mfma_f32_16x16x32_f16(a1[i], b1[j], accf[i][j], 0, 0, 0);
#pragma unroll
        for (int i = 0; i < 4; ++i)
#pragma unroll
            for (int j = 0; j < 2; ++j)
                accf[i][j] = __builtin_amdgcn_mfma_f32_16x16x32_f16(a1[i], b2[j], accf[i][j], 0, 0, 0);
#pragma unroll
        for (int i = 0; i < 4; ++i)
#pragma unroll
            for (int j = 0; j < 2; ++j)
                accf[i][j] = __builtin_amdgcn_mfma_f32_16x16x32_f16(a2[i], b1[j], accf[i][j], 0, 0, 0);

        if ((kt & 3) == 3) {                   // f64 promote every K=128 chunk
#pragma unroll
            for (int i = 0; i < 4; ++i)
#pragma unroll
                for (int j = 0; j < 2; ++j) {
#pragma unroll
                    for (int r = 0; r < 4; ++r)
                        accd[i][j][r] += (double)accf[i][j][r] * SCALE_INV;
                    accf[i][j] = (floatx4){0.f, 0.f, 0.f, 0.f};
                }
        }
    }

#pragma unroll
    for (int i = 0; i < 4; ++i)
#pragma unroll
        for (int j = 0; j < 2; ++j)
#pragma unroll
            for (int r = 0; r < 4; ++r) {
                int row = m0 + wr + i * 16 + quad * 4 + r;
                int col = n0 + wc + j * 16 + l16;
                float f = (float)(accd[i][j][r] + (double)bias[col]);
                f = fmaxf(f, 0.f);             // relu (G1)
                Cout[(size_t)row * N + col] = f;
            }
}

// x [M][K] fp32 -> xs [M][2K] halves, blocked [ktile][plane][kchunk][8].
// Uses cvt_pkrtz -> bit-identical to the in-register split path.
__global__ void split_x(const float* __restrict__ in, _Float16* __restrict__ outS, int n8)
{
    int i = blockIdx.x * 256 + threadIdx.x;
    if (i >= n8) return;
    const int K = INDIM;
    int m  = i / (K / 8);
    int k8 = i % (K / 8);
    int k  = k8 * 8;
    const float* src = in + (size_t)m * K + k;
    floatx4 f0 = *(const floatx4*)(src);
    floatx4 f1 = *(const floatx4*)(src + 4);
    union { half8 v; fp16x2 h[4]; } u1, u2;
    float sv[8];
#pragma unroll
    for (int q = 0; q < 4; ++q) sv[q] = f0[q] * XS;
#pragma unroll
    for (int q = 0; q < 4; ++q) sv[4 + q] = f1[q] * XS;
#pragma unroll
    for (int q = 0; q < 4; ++q) {
        fp16x2 hi = __builtin_amdgcn_cvt_pkrtz(sv[2 * q], sv[2 * q + 1]);
        u1.h[q] = hi;
        float r0 = sv[2 * q] - (float)hi[0];
        float r1 = sv[2 * q + 1] - (float)hi[1];
        u2.h[q] = __builtin_amdgcn_cvt_pkrtz(r0, r1);
    }
    size_t base = (size_t)m * (2 * K) + (size_t)(k >> 5) * 64 + (k & 31);
    *(half8*)(outS + base)      = u1.v;     // plane 0
    *(half8*)(outS + base + 32) = u2.v;     // plane 1
}

// W [K][N] fp32 -> [N][2K] halves (same blocked layout), transposed.
__global__ void transpose_split_f16(const float* __restrict__ in, _Float16* __restrict__ outS,
                                    int K, int N)
{
    __shared__ float tile[32][33];
    int k0 = blockIdx.x * 32, n0 = blockIdx.y * 32;
    int tr = threadIdx.x >> 5, tc = threadIdx.x & 31;
#pragma unroll
    for (int s = 0; s < 4; ++s)
        tile[tr + 8 * s][tc] = in[(size_t)(k0 + tr + 8 * s) * N + n0 + tc];
    __syncthreads();
#pragma unroll
    for (int s = 0; s < 4; ++s) {
        int n = n0 + tr + 8 * s;
        int k = k0 + tc;
        float w = tile[tc][tr + 8 * s] * WS;
        _Float16 p0 = (_Float16)w;
        float r = w - (float)p0;
        _Float16 p1 = (_Float16)r;
        size_t base = (size_t)n * (2 * K) + (size_t)(k >> 5) * 64 + (k & 31);
        outS[base]      = p0;
        outS[base + 32] = p1;
    }
}

// ---------------------------------------------------------------------------
// rownorm32[k] = fl32( sum_fp64( fl32(row[k][d]^2) ) ). One wave per row.
// ---------------------------------------------------------------------------
__global__ void rownorm_kernel(const float* __restrict__ M, float* __restrict__ nrm)
{
    int k = blockIdx.x * 4 + (threadIdx.x >> 6);
    int lane = threadIdx.x & 63;
    float2 c = *(const float2*)(M + (size_t)k * DDIM + lane * 2);
    float q0 = c.x * c.x;
    float q1 = c.y * c.y;
    double s = (double)q0 + (double)q1;
#pragma unroll
    for (int off = 32; off > 0; off >>= 1) s += __shfl_down(s, off);
    if (lane == 0) nrm[k] = (float)s;
}

// max over cn32 (one block).
__global__ void cnmax_kernel(const float* __restrict__ cn, float* __restrict__ out)
{
    __shared__ float red[4];
    int t = threadIdx.x;
    float m = 0.f;
    for (int i = t; i < KCB; i += 256) m = fmaxf(m, cn[i]);
#pragma unroll
    for (int off = 32; off > 0; off >>= 1) m = fmaxf(m, __shfl_down(m, off));
    if ((t & 63) == 0) red[t >> 6] = m;
    __syncthreads();
    if (t == 0) out[0] = fmaxf(fmaxf(red[0], red[1]), fmaxf(red[2], red[3]));
}

// fp32 -> fp16 (optionally scaled by an exact power of two), 8 elems/thread.
__global__ void cvt_half(const float* __restrict__ in, _Float16* __restrict__ out,
                         float scale, int n8)
{
    int i = blockIdx.x * 256 + threadIdx.x;
    if (i >= n8) return;
    const float4 a = *(const float4*)(in + (size_t)i * 8);
    const float4 b = *(const float4*)(in + (size_t)i * 8 + 4);
    half8 h;
    h[0] = (_Float16)(a.x * scale); h[1] = (_Float16)(a.y * scale);
    h[2] = (_Float16)(a.z * scale); h[3] = (_Float16)(a.w * scale);
    h[4] = (_Float16)(b.x * scale); h[5] = (_Float16)(b.y * scale);
    h[6] = (_Float16)(b.z * scale); h[7] = (_Float16)(b.w * scale);
    *(half8*)(out + (size_t)i * 8) = h;
}

// ---------------------------------------------------------------------------
// fp16 approximate score sweeps (R8). EMIT=0: approx min; EMIT=1: candidates.
// ---------------------------------------------------------------------------
template <int EMIT>
__launch_bounds__(256)
__global__ void score_sweep(const _Float16* __restrict__ zh, const _Float16* __restrict__ ch,
                            const float* __restrict__ nz32, const float* __restrict__ cn32,
                            unsigned long long* __restrict__ gbestA,
                            const float* __restrict__ cnmaxp,
                            unsigned* __restrict__ listCnt, unsigned* __restrict__ list)
{
    __shared__ __align__(16) _Float16 As[128 * 128];
    __shared__ __align__(16) _Float16 Bs[128 * 128];
    __shared__ unsigned long long best[128];

    const int t    = threadIdx.x;
    const int m0   = blockIdx.y * 128;   // rows
    const int n0   = blockIdx.x * 128;   // codes
    const int wave = t >> 6, lane = t & 63;
    const int wr   = (wave >> 1) * 64, wc = (wave & 1) * 64;
    const int quad = lane >> 4, l16 = lane & 15;

    if (EMIT == 0 && t < 128) best[t] = ~0ull;

    const int srow = lane >> 4;
    const int sc   = lane & 15;
#pragma unroll
    for (int s = 0; s < 8; ++s) {
        const int rbase = wave * 32 + s * 4;
        const int ra = rbase + srow;
        const int cs = sc ^ ((ra & 7) << 1);
        gll16((const float*)(zh + (size_t)(m0 + ra) * 128 + cs * 8),
              (float*)&As[rbase * 128]);
        gll16((const float*)(ch + (size_t)(n0 + ra) * 128 + cs * 8),
              (float*)&Bs[rbase * 128]);
    }
    __syncthreads();

    floatx4 acc[4][4];
#pragma unroll
    for (int i = 0; i < 4; ++i)
#pragma unroll
        for (int j = 0; j < 4; ++j) acc[i][j] = (floatx4){0.f, 0.f, 0.f, 0.f};

#pragma unroll
    for (int ks = 0; ks < 4; ++ks) {
        half8 af[4], bfr[4];
#pragma unroll
        for (int i = 0; i < 4; ++i) {
            const int rl = wr + i * 16 + l16;
            const int cc = (ks * 4 + quad) ^ ((rl & 7) << 1);
            af[i] = *(const half8*)&As[rl * 128 + cc * 8];
        }
#pragma unroll
        for (int j = 0; j < 4; ++j) {
            const int rl = wc + j * 16 + l16;
            const int cc = (ks * 4 + quad) ^ ((rl & 7) << 1);
            bfr[j] = *(const half8*)&Bs[rl * 128 + cc * 8];
        }
#pragma unroll
        for (int i = 0; i < 4; ++i)
#pragma unroll
            for (int j = 0; j < 4; ++j)
                acc[i][j] = __builtin_amdgcn_mfma_f32_16x16x32_f16(af[i], bfr[j], acc[i][j], 0, 0, 0);
    }

    const float cnm = *cnmaxp;
#pragma unroll
    for (int i = 0; i < 4; ++i)
#pragma unroll
        for (int r = 0; r < 4; ++r) {
            const int lrow = wr + i * 16 + quad * 4 + r;
            const int grow = m0 + lrow;
            const float nz = nz32[grow];
            if (EMIT) {
                const float minA = unpack_d(gbestA[grow]);
                const float thr  = minA + 2.4e-3f * sqrtf(nz * cnm) + 6.0e-5f;
#pragma unroll
                for (int j = 0; j < 4; ++j) {
                    const int code = n0 + wc + j * 16 + l16;
                    float s = acc[i][j][r] * (1.0f / 4096.0f);
                    float d = (nz - 2.0f * s) + cn32[code];
                    if (d <= thr) {
                        unsigned idx = atomicAdd(listCnt, 1u);
                        if (idx < CAND_CAP)
                            list[idx] = ((unsigned)grow << 13) | (unsigned)code;
                    }
                }
            } else {
                float bd = 3.4e38f; int bc = 0x7fffffff;
#pragma unroll
                for (int j = 0; j < 4; ++j) {
                    const int code = n0 + wc + j * 16 + l16;
                    float s = acc[i][j][r] * (1.0f / 4096.0f);
                    float d = (nz - 2.0f * s) + cn32[code];
                    if (d < bd || (d == bd && code < bc)) { bd = d; bc = code; }
                }
                atomicMin(&best[lrow], pack_key(bd, bc));
            }
        }

    if (EMIT == 0) {
        __syncthreads();
        if (t < 128) atomicMin(&gbestA[m0 + t], best[t]);
    }
}

// Exact refine: one wave per candidate pair.
__launch_bounds__(256)
__global__ void refine_kernel(const float* __restrict__ z, const float* __restrict__ cb,
                              const float* __restrict__ nz32, const float* __restrict__ cn32,
                              const unsigned* __restrict__ listCnt,
                              const unsigned* __restrict__ list,
                              unsigned long long* __restrict__ gbest)
{
    unsigned cnt = *listCnt;
    if (cnt > CAND_CAP) cnt = CAND_CAP;
    const int lane = threadIdx.x & 63;
    for (unsigned p = blockIdx.x * 4 + (threadIdx.x >> 6); p < cnt; p += gridDim.x * 4) {
        const unsigned e = list[p];
        const int r = (int)(e >> 13), k = (int)(e & 8191u);
        float2 zv = *(const float2*)(z  + (size_t)r * DDIM + lane * 2);
        float2 cv = *(const float2*)(cb + (size_t)k * DDIM + lane * 2);
        double s = (double)zv.x * (double)cv.x + (double)zv.y * (double)cv.y;
#pragma unroll
        for (int off = 32; off > 0; off >>= 1) s += __shfl_down(s, off);
        if (lane == 0) {
            float s32 = (float)s;
            float d = (nz32[r] - 2.0f * s32) + cn32[k];
            atomicMin(&gbest[r], pack_key(d, k));
        }
    }
}

__global__ void init_gbest(unsigned long long* __restrict__ g)
{
    g[blockIdx.x * 256 + threadIdx.x] = ~0ull;
}

// Gather z_q = codebook[idx] (fp32) and accumulate sum((z_q - z32)^2) in fp64.
__global__ void gather_zq_loss(const float* __restrict__ z, const float* __restrict__ cb,
                               const unsigned long long* __restrict__ gbest,
                               float* __restrict__ zq, double* __restrict__ acc)
{
    int r = blockIdx.x * 4 + (threadIdx.x >> 6);
    int lane = threadIdx.x & 63;
    int k = (int)(gbest[r] & 0xffffffffull);
    float2 zv = *(const float2*)(z  + (size_t)r * DDIM + lane * 2);
    float2 cv = *(const float2*)(cb + (size_t)k * DDIM + lane * 2);
    *(float2*)(zq + (size_t)r * DDIM + lane * 2) = cv;
    double dx = (double)cv.x - (double)zv.x, dy = (double)cv.y - (double)zv.y;
    double s = dx * dx + dy * dy;
#pragma unroll
    for (int off = 32; off > 0; off >>= 1) s += __shfl_down(s, off);
    if (lane == 0) atomicAdd(acc, s);
}

__global__ void init_scalars(double* acc, unsigned* cnt)
{
    if (threadIdx.x == 0 && blockIdx.x == 0) { *acc = 0.0; *cnt = 0u; }
}

__global__ void finalize_kernel(const unsigned long long* __restrict__ gbest,
                                const double* __restrict__ acc, float* __restrict__ out)
{
    int tid = blockIdx.x * 256 + threadIdx.x;
    if (tid < B_) out[16777217 + tid] = (float)(int)(gbest[tid] & 0xffffffffull);
    if (tid == 0) out[16777216] = (float)((*acc) * 1.25 / (double)(B_ * DDIM));
}

// ---------------------------------------------------------------------------
// One-time weight transposes: fp32 [K][N] -> bf16 [N][K].
// ---------------------------------------------------------------------------
__global__ void transpose_to_bf16(const float* __restrict__ in, __bf16* __restrict__ outT,
                                  int K, int N)
{
    __shared__ float tile[32][33];
    int k0 = blockIdx.x * 32, n0 = blockIdx.y * 32;
    int tr = threadIdx.x >> 5, tc = threadIdx.x & 31;
#pragma unroll
    for (int s = 0; s < 4; ++s)
        tile[tr + 8 * s][tc] = in[(size_t)(k0 + tr + 8 * s) * N + n0 + tc];
    __syncthreads();
#pragma unroll
    for (int s = 0; s < 4; ++s)
        outT[(size_t)(n0 + tr + 8 * s) * K + k0 + tc] = (__bf16)tile[tc][tr + 8 * s];
}

// ---------------------------------------------------------------------------
// bf16 MFMA GEMM (decoder): C = act(A@B + bias).
// ---------------------------------------------------------------------------
template <bool A_F32, int ACT>
__launch_bounds__(256)
__global__ void gemm_mfma(const void* __restrict__ Ap, const __bf16* __restrict__ BT,
                          const float* __restrict__ bias, void* __restrict__ Cp,
                          int M, int N, int K)
{
    __shared__ __bf16 Asm[128 * 32];
    __shared__ __bf16 Bsm[128 * 32];

    const int t    = threadIdx.x;
    const int m0   = blockIdx.y * 128, n0 = blockIdx.x * 128;
    const int wave = t >> 6, lane = t & 63;
    const int wr   = (wave >> 1) * 64, wc = (wave & 1) * 64;
    const int quad = lane >> 4, l16 = lane & 15;
    const int sr   = t >> 1, sh = t & 1;

    floatx4 acc[4][4];
#pragma unroll
    for (int i = 0; i < 4; ++i)
#pragma unroll
        for (int j = 0; j < 4; ++j) acc[i][j] = (floatx4){0.f, 0.f, 0.f, 0.f};

    for (int k0 = 0; k0 < K; k0 += 32) {
        if (A_F32) {
            const float* src = (const float*)Ap + (size_t)(m0 + sr) * K + k0 + sh * 16;
            __bf16 tmp[16];
#pragma unroll
            for (int q = 0; q < 4; ++q) {
                float4 v = *(const float4*)(src + q * 4);
                tmp[q * 4 + 0] = (__bf16)v.x; tmp[q * 4 + 1] = (__bf16)v.y;
                tmp[q * 4 + 2] = (__bf16)v.z; tmp[q * 4 + 3] = (__bf16)v.w;
            }
            *(bf16x8*)&Asm[sr * 32 + sh * 16 + 0] = *(bf16x8*)&tmp[0];
            *(bf16x8*)&Asm[sr * 32 + sh * 16 + 8] = *(bf16x8*)&tmp[8];
        } else {
            const __bf16* src = (const __bf16*)Ap + (size_t)(m0 + sr) * K + k0 + sh * 16;
            *(uint4*)&Asm[sr * 32 + sh * 16] = *(const uint4*)src;
            *(uint4*)&Asm[sr * 32 + sh * 16 + 8] = *(const uint4*)(src + 8);
        }
        {
            const __bf16* src = BT + (size_t)(n0 + sr) * K + k0 + sh * 16;
            *(uint4*)&Bsm[sr * 32 + sh * 16] = *(const uint4*)src;
            *(uint4*)&Bsm[sr * 32 + sh * 16 + 8] = *(const uint4*)(src + 8);
        }
        __syncthreads();
        bf16x8 af[4], bfr[4];
#pragma unroll
        for (int i = 0; i < 4; ++i)
            af[i] = *(const bf16x8*)&Asm[(wr + i * 16 + l16) * 32 + quad * 8];
#pragma unroll
        for (int j = 0; j < 4; ++j)
            bfr[j] = *(const bf16x8*)&Bsm[(wc + j * 16 + l16) * 32 + quad * 8];
#pragma unroll
        for (int i = 0; i < 4; ++i)
#pragma unroll
            for (int j = 0; j < 4; ++j)
                acc[i][j] = __builtin_amdgcn_mfma_f32_16x16x32_bf16(af[i], bfr[j], acc[i][j], 0, 0, 0);
        __syncthreads();
    }

#pragma unroll
    for (int i = 0; i < 4; ++i)
#pragma unroll
        for (int j = 0; j < 4; ++j) {
            int col = n0 + wc + j * 16 + l16;
            float b = bias[col];
#pragma unroll
            for (int r = 0; r < 4; ++r) {
                int row = m0 + wr + i * 16 + quad * 4 + r;
                float v = acc[i][j][r] + b;
                if (ACT == 1) {
                    v = fmaxf(v, 0.f);
                    ((__bf16*)Cp)[(size_t)row * N + col] = (__bf16)v;
                } else {
                    v = 1.f / (1.f + __expf(-v));
                    ((float*)Cp)[(size_t)row * N + col] = v;
                }
            }
        }
}

// ---------------------------------------------------------------------------
extern "C" void kernel_launch(void* const* d_in, const int* in_sizes, int n_in,
                              void* d_out, int out_size, void* d_ws, size_t ws_size,
                              hipStream_t stream)
{
    const float* x  = (const float*)d_in[0];
    const float* W1 = (const float*)d_in[1];
    const float* b1 = (const float*)d_in[2];
    const float* W2 = (const float*)d_in[3];
    const float* b2 = (const float*)d_in[4];
    const float* cb = (const float*)d_in[5];
    const float* W3 = (const float*)d_in[6];
    const float* b3 = (const float*)d_in[7];
    const float* W4 = (const float*)d_in[8];
    const float* b4 = (const float*)d_in[9];
    float* out = (float*)d_out;

    char* ws = (char*)d_ws;
    // h fp32 (128MB) live G1->G2 only; h2b bf16 (decoder) aliases at +16MB.
    // Dead-h region [0,16MB) hosts post-G2 score scratch (zh/ch/gbestA/list).
    // W1s fp16-split planes (8MB, live only during G1/G2 prep) alias zq.
    float*  h    = (float*)(ws);
    __bf16* h2b  = (__bf16*)(ws + 16777216ull);       // 64 MB
    float*  z32  = (float*)(ws + 134217728ull);       //  8 MB
    float*  zq   = (float*)(ws + 142606336ull);       //  8 MB
    _Float16* W1s = (_Float16*)(ws + 142606336ull);   //  8 MB (alias of zq)
    float*  nz32 = (float*)(ws + 150994944ull);       // 64 KB
    float*  cn32 = (float*)(ws + 151060480ull);       // 32 KB
    unsigned long long* gbest = (unsigned long long*)(ws + 151093248ull); // 128 KB
    double* acc  = (double*)(ws + 151224320ull);      // 8 B (4KB pad)
    float*  cnmax   = (float*)(ws + 151224328ull);    // 4 B (in acc pad)
    unsigned* listCnt = (unsigned*)(ws + 151224332ull); // 4 B (in acc pad)
    __bf16* W3t  = (__bf16*)(ws + 151228416ull);      // 512 KB [2048][128]
    __bf16* W4t  = (__bf16*)(ws + 151752704ull);      //   4 MB [1024][2048]
    _Float16* W2s = (_Float16*)(ws + 155947008ull);   //   1 MB [128][2*2048]

    _Float16* zh  = (_Float16*)(ws);                  // dead-h region (post-G2)
    _Float16* chh = (_Float16*)(ws + 4194304ull);
    unsigned long long* gbestA = (unsigned long long*)(ws + 6291456ull);
    unsigned* list = (unsigned*)(ws + 8388608ull);

    // xs (pre-split x, 64MB) lives past the 150MB mark -- only if ws allows.
    const unsigned long long XS_OFF = 157286400ull;   // 150 MB
    _Float16* xs = (_Float16*)(ws + XS_OFF);
    const bool pre_split_x = (ws_size >= XS_OFF + 67108864ull);

    init_scalars<<<1, 64, 0, stream>>>(acc, listCnt);
    init_gbest<<<B_ / 256, 256, 0, stream>>>(gbest);
    rownorm_kernel<<<KCB / 4, 256, 0, stream>>>(cb, cn32);
    cnmax_kernel<<<1, 256, 0, stream>>>(cn32, cnmax);
    transpose_to_bf16<<<dim3(DDIM / 32, HID / 32), 256, 0, stream>>>(W3, W3t, DDIM, HID);
    transpose_to_bf16<<<dim3(HID / 32, INDIM / 32), 256, 0, stream>>>(W4, W4t, HID, INDIM);
    transpose_split_f16<<<dim3(INDIM / 32, HID / 32), 256, 0, stream>>>(W1, W1s, INDIM, HID);
    transpose_split_f16<<<dim3(HID / 32, DDIM / 32), 256, 0, stream>>>(W2, W2s, HID, DDIM);

    // h = relu(x@W1 + b1), 3-pass split-fp16 MFMA  [16384,1024]x[1024,2048]
    if (pre_split_x) {
        split_x<<<(B_ * INDIM / 8) / 256, 256, 0, stream>>>(x, xs, B_ * INDIM / 8);
        gemm_split_pre<<<dim3(HID / 64, B_ / 128), 256, 0, stream>>>(
            xs, W1s, b1, h, B_, HID, INDIM);
    } else {
        gemm_split_f16<1, 3><<<dim3(HID / 64, B_ / 128), 256, 0, stream>>>(
            x, W1s, b1, h, B_, HID, INDIM);
    }
    // z32 = h@W2 + b2, 3-pass split-fp16 (K=64 promote) [16384,2048]x[2048,128]
    gemm_split_f16<0, 1><<<dim3(DDIM / 64, B_ / 128), 256, 0, stream>>>(
        h, W2s, b2, z32, B_, DDIM, HID);
    // nz32 = fl32(sum fl32(z^2))
    rownorm_kernel<<<B_ / 4, 256, 0, stream>>>(z32, nz32);

    // --- fast score path: fp16 sweeps + exact refine ---
    init_gbest<<<B_ / 256, 256, 0, stream>>>(gbestA);
    cvt_half<<<(B_ * DDIM / 8) / 256, 256, 0, stream>>>(z32, zh, 1.0f, B_ * DDIM / 8);
    cvt_half<<<(KCB * DDIM / 8) / 256, 256, 0, stream>>>(cb, chh, 4096.0f, KCB * DDIM / 8);
    score_sweep<0><<<dim3(KCB / 128, B_ / 128), 256, 0, stream>>>(
        zh, chh, nz32, cn32, gbestA, cnmax, listCnt, list);
    score_sweep<1><<<dim3(KCB / 128, B_ / 128), 256, 0, stream>>>(
        zh, chh, nz32, cn32, gbestA, cnmax, listCnt, list);
    refine_kernel<<<1024, 256, 0, stream>>>(z32, cb, nz32, cn32, listCnt, list, gbest);

    // z_q gather + commitment loss
    gather_zq_loss<<<B_ / 4, 256, 0, stream>>>(z32, cb, gbest, zq, acc);
    // h2 = relu(zq@W3 + b3) -> bf16               [16384,128]x[128,2048]
    gemm_mfma<true, 1><<<dim3(HID / 128, B_ / 128), 256, 0, stream>>>(
        (const void*)zq, W3t, b3, (void*)h2b, B_, HID, DDIM);
    // recon = sigmoid(h2@W4 + b4) -> fp32 out     [16384,2048]x[2048,1024]
    gemm_mfma<false, 2><<<dim3(INDIM / 128, B_ / 128), 256, 0, stream>>>(
        (const void*)h2b, W4t, b4, (void*)out, B_, INDIM, HID);

    finalize_kernel<<<B_ / 256, 256, 0, stream>>>(gbest, acc, out);
}

// Round 5
// 990.208 us; speedup vs baseline: 2.5415x; 1.3360x over previous
//
#include <hip/hip_runtime.h>
#include <hip/hip_bf16.h>

// VQ-VAE forward. R12: score sweeps restructured from single-shot 128x128
// blocks (latency-bound, 4.6% MfmaUtil, 291us) into N-loop GEMM-style kernels:
// block owns 32 z-rows, loops all 64 code-tiles with 2-barrier gll16 staging,
// A-fragments hoisted to registers, per-lane running min in regs (EMIT=0) /
// LDS-buffered candidate emission (EMIT=1, 256 global atomics vs 21k).
// Same d-formula both passes -> rigorous Cauchy-Schwarz window preserved,
// gbest bit-identical. G1: pre-split 3-pass fp16 GEMM; G2: split-fp16 with
// in-register A split; decoder: bf16 MFMA.
// Outputs (flat fp32): recon[16384*1024], loss[1], indices-as-float[16384].

#define B_    16384
#define INDIM 1024
#define HID   2048
#define KCB   8192
#define DDIM  128

#define CAND_CAP 2000000u
#define LBUF_CAP 1024u

typedef __bf16    bf16x8   __attribute__((ext_vector_type(8)));
typedef float     floatx4  __attribute__((ext_vector_type(4)));
typedef double    doublex4 __attribute__((ext_vector_type(4)));
typedef _Float16  half8    __attribute__((ext_vector_type(8)));
typedef __fp16    fp16x2   __attribute__((ext_vector_type(2)));

// split scales (exact powers of two)
#define XS 4096.0f              // 2^12 on A (x or h)
#define WS 8192.0f              // 2^13 on W
#define SCALE_INV 2.9802322387695312e-08  // 2^-25

__device__ __forceinline__ unsigned long long pack_key(float d, int code)
{
    unsigned int u = __float_as_uint(d);
    u = (u & 0x80000000u) ? ~u : (u | 0x80000000u);   // total order matching float <
    return ((unsigned long long)u << 32) | (unsigned int)code;
}

__device__ __forceinline__ float unpack_d(unsigned long long key)
{
    unsigned int u = (unsigned int)(key >> 32);
    u = (u & 0x80000000u) ? (u ^ 0x80000000u) : ~u;
    return __uint_as_float(u);
}

// Async global->LDS, 16 B per lane. LDS dest: wave-uniform base + lane*16.
__device__ __forceinline__ void gll16(const float* g, float* l)
{
    __builtin_amdgcn_global_load_lds(
        (const __attribute__((address_space(1))) void*)g,
        (__attribute__((address_space(3))) void*)l, 16, 0, 0);
}

// ---------------------------------------------------------------------------
// Split-fp16 GEMM, A fp32 with IN-REGISTER split (proven R10 kernel).
// ACT: 1 = relu. PMASK: f64-promote every (PMASK+1) k-tiles. Used for G2.
// ---------------------------------------------------------------------------
template <int ACT, int PMASK>
__launch_bounds__(256)
__global__ void gemm_split_f16(const float* __restrict__ A, const _Float16* __restrict__ Bs_g,
                               const float* __restrict__ bias, float* __restrict__ Cout,
                               int M, int N, int K)
{
    __shared__ float    As[128 * 32];       // [row][8 slots][4 floats]
    __shared__ _Float16 Bsh[64 * 64];       // [row][8 slots][8 halves]

    const int t    = threadIdx.x;
    const int m0   = blockIdx.y * 128, n0 = blockIdx.x * 64;
    const int wave = t >> 6, lane = t & 63;
    const int wr   = (wave >> 1) * 64, wc = (wave & 1) * 32;
    const int quad = lane >> 4, l16 = lane & 15;
    const int lr   = lane >> 3;
    const int lcA  = ((lane & 7) ^ lr) * 4;
    const int slB  = lane & 7;
    const int lrB  = lane >> 3;

    floatx4  accf[4][2];
    doublex4 accd[4][2];
#pragma unroll
    for (int i = 0; i < 4; ++i)
#pragma unroll
        for (int j = 0; j < 2; ++j) {
            accf[i][j] = (floatx4){0.f, 0.f, 0.f, 0.f};
            accd[i][j] = (doublex4){0.0, 0.0, 0.0, 0.0};
        }

    const int NKT = K >> 5;
    for (int kt = 0; kt < NKT; ++kt) {
        const int k0 = kt << 5;
        __syncthreads();
#pragma unroll
        for (int s = 0; s < 4; ++s) {
            int r = wave * 32 + s * 8;
            gll16(A + (size_t)(m0 + r + lr) * K + k0 + lcA, &As[r * 32]);
        }
#pragma unroll
        for (int s = 0; s < 2; ++s) {
            int rb = wave * 16 + s * 8 + lrB;
            int ccs = slB ^ (lrB & 7);
            gll16((const float*)(Bs_g + (size_t)(n0 + rb) * (2 * K) + kt * 64 + ccs * 8),
                  (float*)&Bsh[(wave * 16 + s * 8) * 64]);
        }
        __syncthreads();

        half8 a1[4], a2[4];
#pragma unroll
        for (int i = 0; i < 4; ++i) {
            const int row = wr + i * 16 + l16;
            const int s0  = (2 * quad) ^ (row & 7);
            const int s1  = (2 * quad + 1) ^ (row & 7);
            floatx4 f0 = *(const floatx4*)&As[row * 32 + s0 * 4];
            floatx4 f1 = *(const floatx4*)&As[row * 32 + s1 * 4];
            union { half8 v; fp16x2 h[4]; } u1, u2;
            float sv[8];
#pragma unroll
            for (int q = 0; q < 4; ++q) sv[q] = f0[q] * XS;
#pragma unroll
            for (int q = 0; q < 4; ++q) sv[4 + q] = f1[q] * XS;
#pragma unroll
            for (int q = 0; q < 4; ++q) {
                fp16x2 hi = __builtin_amdgcn_cvt_pkrtz(sv[2 * q], sv[2 * q + 1]);
                u1.h[q] = hi;
                float r0 = sv[2 * q] - (float)hi[0];
                float r1 = sv[2 * q + 1] - (float)hi[1];
                u2.h[q] = __builtin_amdgcn_cvt_pkrtz(r0, r1);
            }
            a1[i] = u1.v; a2[i] = u2.v;
        }
        half8 b1[2], b2[2];
#pragma unroll
        for (int j = 0; j < 2; ++j) {
            const int row = wc + j * 16 + l16;
            b1[j] = *(const half8*)&Bsh[row * 64 + ((0 + quad) ^ (row & 7)) * 8];
            b2[j] = *(const half8*)&Bsh[row * 64 + ((4 + quad) ^ (row & 7)) * 8];
        }
#pragma unroll
        for (int i = 0; i < 4; ++i)
#pragma unroll
            for (int j = 0; j < 2; ++j)
                accf[i][j] = __builtin_amdgcn_mfma_f32_16x16x32_f16(a1[i], b1[j], accf[i][j], 0, 0, 0);
#pragma unroll
        for (int i = 0; i < 4; ++i)
#pragma unroll
            for (int j = 0; j < 2; ++j)
                accf[i][j] = __builtin_amdgcn_mfma_f32_16x16x32_f16(a1[i], b2[j], accf[i][j], 0, 0, 0);
#pragma unroll
        for (int i = 0; i < 4; ++i)
#pragma unroll
            for (int j = 0; j < 2; ++j)
                accf[i][j] = __builtin_amdgcn_mfma_f32_16x16x32_f16(a2[i], b1[j], accf[i][j], 0, 0, 0);

        if ((kt & PMASK) == PMASK) {
#pragma unroll
            for (int i = 0; i < 4; ++i)
#pragma unroll
                for (int j = 0; j < 2; ++j) {
#pragma unroll
                    for (int r = 0; r < 4; ++r)
                        accd[i][j][r] += (double)accf[i][j][r] * SCALE_INV;
                    accf[i][j] = (floatx4){0.f, 0.f, 0.f, 0.f};
                }
        }
    }
    if (NKT & PMASK) {
#pragma unroll
        for (int i = 0; i < 4; ++i)
#pragma unroll
            for (int j = 0; j < 2; ++j)
#pragma unroll
                for (int r = 0; r < 4; ++r)
                    accd[i][j][r] += (double)accf[i][j][r] * SCALE_INV;
    }

#pragma unroll
    for (int i = 0; i < 4; ++i)
#pragma unroll
        for (int j = 0; j < 2; ++j)
#pragma unroll
            for (int r = 0; r < 4; ++r) {
                int row = m0 + wr + i * 16 + quad * 4 + r;
                int col = n0 + wc + j * 16 + l16;
                float f = (float)(accd[i][j][r] + (double)bias[col]);
                if (ACT == 1) f = fmaxf(f, 0.f);
                Cout[(size_t)row * N + col] = f;
            }
}

// ---------------------------------------------------------------------------
// Split-fp16 GEMM, BOTH operands pre-split [rows][2*K] halves (per 32-k tile:
// [plane(2)][kchunk(4)][8 halves]). Zero per-element VALU in the K-loop.
// ---------------------------------------------------------------------------
__launch_bounds__(256)
__global__ void gemm_split_pre(const _Float16* __restrict__ As_g, const _Float16* __restrict__ Bs_g,
                               const float* __restrict__ bias, float* __restrict__ Cout,
                               int M, int N, int K)
{
    __shared__ _Float16 Ash[128 * 64];      // [row][8 slots][8 halves]
    __shared__ _Float16 Bsh[64 * 64];

    const int t    = threadIdx.x;
    const int m0   = blockIdx.y * 128, n0 = blockIdx.x * 64;
    const int wave = t >> 6, lane = t & 63;
    const int wr   = (wave >> 1) * 64, wc = (wave & 1) * 32;
    const int quad = lane >> 4, l16 = lane & 15;
    const int slB  = lane & 7;
    const int lrB  = lane >> 3;
    const int ccs  = slB ^ (lrB & 7);

    floatx4  accf[4][2];
    doublex4 accd[4][2];
#pragma unroll
    for (int i = 0; i < 4; ++i)
#pragma unroll
        for (int j = 0; j < 2; ++j) {
            accf[i][j] = (floatx4){0.f, 0.f, 0.f, 0.f};
            accd[i][j] = (doublex4){0.0, 0.0, 0.0, 0.0};
        }

    const int NKT = K >> 5;
    for (int kt = 0; kt < NKT; ++kt) {
        __syncthreads();
#pragma unroll
        for (int s = 0; s < 4; ++s) {
            int ra = wave * 32 + s * 8 + lrB;
            gll16((const float*)(As_g + (size_t)(m0 + ra) * (2 * K) + kt * 64 + ccs * 8),
                  (float*)&Ash[(wave * 32 + s * 8) * 64]);
        }
#pragma unroll
        for (int s = 0; s < 2; ++s) {
            int rb = wave * 16 + s * 8 + lrB;
            gll16((const float*)(Bs_g + (size_t)(n0 + rb) * (2 * K) + kt * 64 + ccs * 8),
                  (float*)&Bsh[(wave * 16 + s * 8) * 64]);
        }
        __syncthreads();

        half8 a1[4], a2[4], b1[2], b2[2];
#pragma unroll
        for (int i = 0; i < 4; ++i) {
            const int row = wr + i * 16 + l16;
            a1[i] = *(const half8*)&Ash[row * 64 + ((0 + quad) ^ (row & 7)) * 8];
            a2[i] = *(const half8*)&Ash[row * 64 + ((4 + quad) ^ (row & 7)) * 8];
        }
#pragma unroll
        for (int j = 0; j < 2; ++j) {
            const int row = wc + j * 16 + l16;
            b1[j] = *(const half8*)&Bsh[row * 64 + ((0 + quad) ^ (row & 7)) * 8];
            b2[j] = *(const half8*)&Bsh[row * 64 + ((4 + quad) ^ (row & 7)) * 8];
        }
#pragma unroll
        for (int i = 0; i < 4; ++i)
#pragma unroll
            for (int j = 0; j < 2; ++j)
                accf[i][j] = __builtin_amdgcn_mfma_f32_16x16x32_f16(a1[i], b1[j], accf[i][j], 0, 0, 0);
#pragma unroll
        for (int i = 0; i < 4; ++i)
#pragma unroll
            for (int j = 0; j < 2; ++j)
                accf[i][j] = __builtin_amdgcn_mfma_f32_16x16x32_f16(a1[i], b2[j], accf[i][j], 0, 0, 0);
#pragma unroll
        for (int i = 0; i < 4; ++i)
#pragma unroll
            for (int j = 0; j < 2; ++j)
                accf[i][j] = __builtin_amdgcn_mfma_f32_16x16x32_f16(a2[i], b1[j], accf[i][j], 0, 0, 0);

        if ((kt & 3) == 3) {
#pragma unroll
            for (int i = 0; i < 4; ++i)
#pragma unroll
                for (int j = 0; j < 2; ++j) {
#pragma unroll
                    for (int r = 0; r < 4; ++r)
                        accd[i][j][r] += (double)accf[i][j][r] * SCALE_INV;
                    accf[i][j] = (floatx4){0.f, 0.f, 0.f, 0.f};
                }
        }
    }

#pragma unroll
    for (int i = 0; i < 4; ++i)
#pragma unroll
        for (int j = 0; j < 2; ++j)
#pragma unroll
            for (int r = 0; r < 4; ++r) {
                int row = m0 + wr + i * 16 + quad * 4 + r;
                int col = n0 + wc + j * 16 + l16;
                float f = (float)(accd[i][j][r] + (double)bias[col]);
                f = fmaxf(f, 0.f);             // relu (G1)
                Cout[(size_t)row * N + col] = f;
            }
}

// x [M][K] fp32 -> xs [M][2K] halves, blocked [ktile][plane][kchunk][8].
__global__ void split_x(const float* __restrict__ in, _Float16* __restrict__ outS, int n8)
{
    int i = blockIdx.x * 256 + threadIdx.x;
    if (i >= n8) return;
    const int K = INDIM;
    int m  = i / (K / 8);
    int k8 = i % (K / 8);
    int k  = k8 * 8;
    const float* src = in + (size_t)m * K + k;
    floatx4 f0 = *(const floatx4*)(src);
    floatx4 f1 = *(const floatx4*)(src + 4);
    union { half8 v; fp16x2 h[4]; } u1, u2;
    float sv[8];
#pragma unroll
    for (int q = 0; q < 4; ++q) sv[q] = f0[q] * XS;
#pragma unroll
    for (int q = 0; q < 4; ++q) sv[4 + q] = f1[q] * XS;
#pragma unroll
    for (int q = 0; q < 4; ++q) {
        fp16x2 hi = __builtin_amdgcn_cvt_pkrtz(sv[2 * q], sv[2 * q + 1]);
        u1.h[q] = hi;
        float r0 = sv[2 * q] - (float)hi[0];
        float r1 = sv[2 * q + 1] - (float)hi[1];
        u2.h[q] = __builtin_amdgcn_cvt_pkrtz(r0, r1);
    }
    size_t base = (size_t)m * (2 * K) + (size_t)(k >> 5) * 64 + (k & 31);
    *(half8*)(outS + base)      = u1.v;     // plane 0
    *(half8*)(outS + base + 32) = u2.v;     // plane 1
}

// W [K][N] fp32 -> [N][2K] halves (same blocked layout), transposed.
__global__ void transpose_split_f16(const float* __restrict__ in, _Float16* __restrict__ outS,
                                    int K, int N)
{
    __shared__ float tile[32][33];
    int k0 = blockIdx.x * 32, n0 = blockIdx.y * 32;
    int tr = threadIdx.x >> 5, tc = threadIdx.x & 31;
#pragma unroll
    for (int s = 0; s < 4; ++s)
        tile[tr + 8 * s][tc] = in[(size_t)(k0 + tr + 8 * s) * N + n0 + tc];
    __syncthreads();
#pragma unroll
    for (int s = 0; s < 4; ++s) {
        int n = n0 + tr + 8 * s;
        int k = k0 + tc;
        float w = tile[tc][tr + 8 * s] * WS;
        _Float16 p0 = (_Float16)w;
        float r = w - (float)p0;
        _Float16 p1 = (_Float16)r;
        size_t base = (size_t)n * (2 * K) + (size_t)(k >> 5) * 64 + (k & 31);
        outS[base]      = p0;
        outS[base + 32] = p1;
    }
}

// ---------------------------------------------------------------------------
// rownorm32[k] = fl32( sum_fp64( fl32(row[k][d]^2) ) ). One wave per row.
// ---------------------------------------------------------------------------
__global__ void rownorm_kernel(const float* __restrict__ M, float* __restrict__ nrm)
{
    int k = blockIdx.x * 4 + (threadIdx.x >> 6);
    int lane = threadIdx.x & 63;
    float2 c = *(const float2*)(M + (size_t)k * DDIM + lane * 2);
    float q0 = c.x * c.x;
    float q1 = c.y * c.y;
    double s = (double)q0 + (double)q1;
#pragma unroll
    for (int off = 32; off > 0; off >>= 1) s += __shfl_down(s, off);
    if (lane == 0) nrm[k] = (float)s;
}

// max over cn32 (one block).
__global__ void cnmax_kernel(const float* __restrict__ cn, float* __restrict__ out)
{
    __shared__ float red[4];
    int t = threadIdx.x;
    float m = 0.f;
    for (int i = t; i < KCB; i += 256) m = fmaxf(m, cn[i]);
#pragma unroll
    for (int off = 32; off > 0; off >>= 1) m = fmaxf(m, __shfl_down(m, off));
    if ((t & 63) == 0) red[t >> 6] = m;
    __syncthreads();
    if (t == 0) out[0] = fmaxf(fmaxf(red[0], red[1]), fmaxf(red[2], red[3]));
}

// fp32 -> fp16 (optionally scaled by an exact power of two), 8 elems/thread.
__global__ void cvt_half(const float* __restrict__ in, _Float16* __restrict__ out,
                         float scale, int n8)
{
    int i = blockIdx.x * 256 + threadIdx.x;
    if (i >= n8) return;
    const float4 a = *(const float4*)(in + (size_t)i * 8);
    const float4 b = *(const float4*)(in + (size_t)i * 8 + 4);
    half8 h;
    h[0] = (_Float16)(a.x * scale); h[1] = (_Float16)(a.y * scale);
    h[2] = (_Float16)(a.z * scale); h[3] = (_Float16)(a.w * scale);
    h[4] = (_Float16)(b.x * scale); h[5] = (_Float16)(b.y * scale);
    h[6] = (_Float16)(b.z * scale); h[7] = (_Float16)(b.w * scale);
    *(half8*)(out + (size_t)i * 8) = h;
}

// ---------------------------------------------------------------------------
// R12 N-loop score sweeps. Block = 32 z-rows x ALL 8192 codes (grid 512).
// z staged once (8KB), A-frags hoisted to regs; 64 code-tile iterations with
// 2-barrier gll16 staging of ch (32KB/iter). 4 waves, wave = 32 rows x 32
// codes (i2 x j2 x ks4 = 16 MFMA/iter). EMIT=0: per-lane running min in regs,
// one LDS pack_key combine, plain gbestA store (exclusive rows). EMIT=1:
// thr preloaded per row; candidates buffered in LDS, one listCnt reservation
// per block (+ safe spill path). d-formula identical in both passes.
// ---------------------------------------------------------------------------
template <int EMIT>
__launch_bounds__(256)
__global__ void score_sweep2(const _Float16* __restrict__ zh, const _Float16* __restrict__ ch,
                             const float* __restrict__ nz32, const float* __restrict__ cn32,
                             unsigned long long* __restrict__ gbestA,
                             const float* __restrict__ cnmaxp,
                             unsigned* __restrict__ listCnt, unsigned* __restrict__ list)
{
    __shared__ __align__(16) _Float16 Zs[32 * 128];    //  8 KB
    __shared__ __align__(16) _Float16 Cs[128 * 128];   // 32 KB
    __shared__ unsigned long long best[32];            // EMIT==0 combine
    __shared__ unsigned lbuf[LBUF_CAP];                // EMIT==1 candidates
    __shared__ unsigned lcnt, lbase;

    const int t    = threadIdx.x;
    const int m0   = blockIdx.x * 32;
    const int wave = t >> 6, lane = t & 63;
    const int quad = lane >> 4, l16 = lane & 15;
    const int srow = lane >> 4, sc = lane & 15;

    if (EMIT == 0) { if (t < 32) best[t] = ~0ull; }
    else if (t == 0) lcnt = 0u;

    // stage z rows once (2 rounds x 4 rows/wave)
#pragma unroll
    for (int s = 0; s < 2; ++s) {
        const int rbase = s * 16 + wave * 4;
        const int ra = rbase + srow;
        const int cs = sc ^ ((ra & 7) << 1);
        gll16((const float*)(zh + (size_t)(m0 + ra) * 128 + cs * 8),
              (float*)&Zs[rbase * 128]);
    }
    __syncthreads();   // z staged (drains vmcnt); best/lcnt init visible

    // hoist A fragments (2 i-frags x 4 k-slices)
    half8 af[2][4];
#pragma unroll
    for (int i = 0; i < 2; ++i) {
        const int rl = i * 16 + l16;
#pragma unroll
        for (int ks = 0; ks < 4; ++ks) {
            const int cc = (ks * 4 + quad) ^ ((rl & 7) << 1);
            af[i][ks] = *(const half8*)&Zs[rl * 128 + cc * 8];
        }
    }

    // per-lane row data (8 rows: i2 x r4)
    const float cnm = *cnmaxp;
    float nzv[8], thr[8], bd[8];
    int   bc[8];
#pragma unroll
    for (int i = 0; i < 2; ++i)
#pragma unroll
        for (int r = 0; r < 4; ++r) {
            const int q = i * 4 + r;
            const int grow = m0 + i * 16 + quad * 4 + r;
            nzv[q] = nz32[grow];
            if (EMIT) {
                thr[q] = unpack_d(gbestA[grow]) + 2.4e-3f * sqrtf(nzv[q] * cnm) + 6.0e-5f;
            } else {
                bd[q] = 3.4e38f; bc[q] = 0x7fffffff;
            }
        }

    for (int nt = 0; nt < KCB / 128; ++nt) {
        const int n0 = nt * 128;
        __syncthreads();   // previous tile's compute done
#pragma unroll
        for (int s = 0; s < 8; ++s) {
            const int rbase = s * 16 + wave * 4;
            const int ra = rbase + srow;
            const int cs = sc ^ ((ra & 7) << 1);
            gll16((const float*)(ch + (size_t)(n0 + ra) * 128 + cs * 8),
                  (float*)&Cs[rbase * 128]);
        }
        __syncthreads();   // tile staged

        floatx4 acc[2][2];
#pragma unroll
        for (int i = 0; i < 2; ++i)
#pragma unroll
            for (int j = 0; j < 2; ++j) acc[i][j] = (floatx4){0.f, 0.f, 0.f, 0.f};
#pragma unroll
        for (int ks = 0; ks < 4; ++ks) {
            half8 bf[2];
#pragma unroll
            for (int j = 0; j < 2; ++j) {
                const int rl = wave * 32 + j * 16 + l16;
                const int cc = (ks * 4 + quad) ^ ((rl & 7) << 1);
                bf[j] = *(const half8*)&Cs[rl * 128 + cc * 8];
            }
#pragma unroll
            for (int i = 0; i < 2; ++i)
#pragma unroll
                for (int j = 0; j < 2; ++j)
                    acc[i][j] = __builtin_amdgcn_mfma_f32_16x16x32_f16(af[i][ks], bf[j], acc[i][j], 0, 0, 0);
        }

#pragma unroll
        for (int i = 0; i < 2; ++i)
#pragma unroll
            for (int r = 0; r < 4; ++r) {
                const int q = i * 4 + r;
#pragma unroll
                for (int j = 0; j < 2; ++j) {       // codes ascending (tie: first wins)
                    const int code = n0 + wave * 32 + j * 16 + l16;
                    float s = acc[i][j][r] * (1.0f / 4096.0f);
                    float d = (nzv[q] - 2.0f * s) + cn32[code];
                    if (EMIT) {
                        if (d <= thr[q]) {
                            unsigned ent = ((unsigned)(m0 + i * 16 + quad * 4 + r) << 13) | (unsigned)code;
                            unsigned idx = atomicAdd(&lcnt, 1u);
                            if (idx < LBUF_CAP) lbuf[idx] = ent;
                            else {                  // spill (rare): direct global
                                unsigned g = atomicAdd(listCnt, 1u);
                                if (g < CAND_CAP) list[g] = ent;
                            }
                        }
                    } else {
                        if (d < bd[q]) { bd[q] = d; bc[q] = code; }
                    }
                }
            }
    }

    if (EMIT == 0) {
#pragma unroll
        for (int i = 0; i < 2; ++i)
#pragma unroll
            for (int r = 0; r < 4; ++r) {
                const int q = i * 4 + r;
                atomicMin(&best[i * 16 + quad * 4 + r], pack_key(bd[q], bc[q]));
            }
        __syncthreads();
        if (t < 32) gbestA[m0 + t] = best[t];
    } else {
        __syncthreads();
        unsigned cnt = lcnt; if (cnt > LBUF_CAP) cnt = LBUF_CAP;
        if (t == 0) lbase = atomicAdd(listCnt, cnt);
        __syncthreads();
        for (unsigned e = t; e < cnt; e += 256) {
            unsigned g = lbase + e;
            if (g < CAND_CAP) list[g] = lbuf[e];
        }
    }
}

// Exact refine: one wave per candidate pair.
__launch_bounds__(256)
__global__ void refine_kernel(const float* __restrict__ z, const float* __restrict__ cb,
                              const float* __restrict__ nz32, const float* __restrict__ cn32,
                              const unsigned* __restrict__ listCnt,
                              const unsigned* __restrict__ list,
                              unsigned long long* __restrict__ gbest)
{
    unsigned cnt = *listCnt;
    if (cnt > CAND_CAP) cnt = CAND_CAP;
    const int lane = threadIdx.x & 63;
    for (unsigned p = blockIdx.x * 4 + (threadIdx.x >> 6); p < cnt; p += gridDim.x * 4) {
        const unsigned e = list[p];
        const int r = (int)(e >> 13), k = (int)(e & 8191u);
        float2 zv = *(const float2*)(z  + (size_t)r * DDIM + lane * 2);
        float2 cv = *(const float2*)(cb + (size_t)k * DDIM + lane * 2);
        double s = (double)zv.x * (double)cv.x + (double)zv.y * (double)cv.y;
#pragma unroll
        for (int off = 32; off > 0; off >>= 1) s += __shfl_down(s, off);
        if (lane == 0) {
            float s32 = (float)s;
            float d = (nz32[r] - 2.0f * s32) + cn32[k];
            atomicMin(&gbest[r], pack_key(d, k));
        }
    }
}

__global__ void init_gbest(unsigned long long* __restrict__ g)
{
    g[blockIdx.x * 256 + threadIdx.x] = ~0ull;
}

// Gather z_q = codebook[idx] (fp32) and accumulate sum((z_q - z32)^2) in fp64.
__global__ void gather_zq_loss(const float* __restrict__ z, const float* __restrict__ cb,
                               const unsigned long long* __restrict__ gbest,
                               float* __restrict__ zq, double* __restrict__ acc)
{
    int r = blockIdx.x * 4 + (threadIdx.x >> 6);
    int lane = threadIdx.x & 63;
    int k = (int)(gbest[r] & 0xffffffffull);
    float2 zv = *(const float2*)(z  + (size_t)r * DDIM + lane * 2);
    float2 cv = *(const float2*)(cb + (size_t)k * DDIM + lane * 2);
    *(float2*)(zq + (size_t)r * DDIM + lane * 2) = cv;
    double dx = (double)cv.x - (double)zv.x, dy = (double)cv.y - (double)zv.y;
    double s = dx * dx + dy * dy;
#pragma unroll
    for (int off = 32; off > 0; off >>= 1) s += __shfl_down(s, off);
    if (lane == 0) atomicAdd(acc, s);
}

__global__ void init_scalars(double* acc, unsigned* cnt)
{
    if (threadIdx.x == 0 && blockIdx.x == 0) { *acc = 0.0; *cnt = 0u; }
}

__global__ void finalize_kernel(const unsigned long long* __restrict__ gbest,
                                const double* __restrict__ acc, float* __restrict__ out)
{
    int tid = blockIdx.x * 256 + threadIdx.x;
    if (tid < B_) out[16777217 + tid] = (float)(int)(gbest[tid] & 0xffffffffull);
    if (tid == 0) out[16777216] = (float)((*acc) * 1.25 / (double)(B_ * DDIM));
}

// ---------------------------------------------------------------------------
// One-time weight transposes: fp32 [K][N] -> bf16 [N][K].
// ---------------------------------------------------------------------------
__global__ void transpose_to_bf16(const float* __restrict__ in, __bf16* __restrict__ outT,
                                  int K, int N)
{
    __shared__ float tile[32][33];
    int k0 = blockIdx.x * 32, n0 = blockIdx.y * 32;
    int tr = threadIdx.x >> 5, tc = threadIdx.x & 31;
#pragma unroll
    for (int s = 0; s < 4; ++s)
        tile[tr + 8 * s][tc] = in[(size_t)(k0 + tr + 8 * s) * N + n0 + tc];
    __syncthreads();
#pragma unroll
    for (int s = 0; s < 4; ++s)
        outT[(size_t)(n0 + tr + 8 * s) * K + k0 + tc] = (__bf16)tile[tc][tr + 8 * s];
}

// ---------------------------------------------------------------------------
// bf16 MFMA GEMM (decoder): C = act(A@B + bias).
// ---------------------------------------------------------------------------
template <bool A_F32, int ACT>
__launch_bounds__(256)
__global__ void gemm_mfma(const void* __restrict__ Ap, const __bf16* __restrict__ BT,
                          const float* __restrict__ bias, void* __restrict__ Cp,
                          int M, int N, int K)
{
    __shared__ __bf16 Asm[128 * 32];
    __shared__ __bf16 Bsm[128 * 32];

    const int t    = threadIdx.x;
    const int m0   = blockIdx.y * 128, n0 = blockIdx.x * 128;
    const int wave = t >> 6, lane = t & 63;
    const int wr   = (wave >> 1) * 64, wc = (wave & 1) * 64;
    const int quad = lane >> 4, l16 = lane & 15;
    const int sr   = t >> 1, sh = t & 1;

    floatx4 acc[4][4];
#pragma unroll
    for (int i = 0; i < 4; ++i)
#pragma unroll
        for (int j = 0; j < 4; ++j) acc[i][j] = (floatx4){0.f, 0.f, 0.f, 0.f};

    for (int k0 = 0; k0 < K; k0 += 32) {
        if (A_F32) {
            const float* src = (const float*)Ap + (size_t)(m0 + sr) * K + k0 + sh * 16;
            __bf16 tmp[16];
#pragma unroll
            for (int q = 0; q < 4; ++q) {
                float4 v = *(const float4*)(src + q * 4);
                tmp[q * 4 + 0] = (__bf16)v.x; tmp[q * 4 + 1] = (__bf16)v.y;
                tmp[q * 4 + 2] = (__bf16)v.z; tmp[q * 4 + 3] = (__bf16)v.w;
            }
            *(bf16x8*)&Asm[sr * 32 + sh * 16 + 0] = *(bf16x8*)&tmp[0];
            *(bf16x8*)&Asm[sr * 32 + sh * 16 + 8] = *(bf16x8*)&tmp[8];
        } else {
            const __bf16* src = (const __bf16*)Ap + (size_t)(m0 + sr) * K + k0 + sh * 16;
            *(uint4*)&Asm[sr * 32 + sh * 16] = *(const uint4*)src;
            *(uint4*)&Asm[sr * 32 + sh * 16 + 8] = *(const uint4*)(src + 8);
        }
        {
            const __bf16* src = BT + (size_t)(n0 + sr) * K + k0 + sh * 16;
            *(uint4*)&Bsm[sr * 32 + sh * 16] = *(const uint4*)src;
            *(uint4*)&Bsm[sr * 32 + sh * 16 + 8] = *(const uint4*)(src + 8);
        }
        __syncthreads();
        bf16x8 af[4], bfr[4];
#pragma unroll
        for (int i = 0; i < 4; ++i)
            af[i] = *(const bf16x8*)&Asm[(wr + i * 16 + l16) * 32 + quad * 8];
#pragma unroll
        for (int j = 0; j < 4; ++j)
            bfr[j] = *(const bf16x8*)&Bsm[(wc + j * 16 + l16) * 32 + quad * 8];
#pragma unroll
        for (int i = 0; i < 4; ++i)
#pragma unroll
            for (int j = 0; j < 4; ++j)
                acc[i][j] = __builtin_amdgcn_mfma_f32_16x16x32_bf16(af[i], bfr[j], acc[i][j], 0, 0, 0);
        __syncthreads();
    }

#pragma unroll
    for (int i = 0; i < 4; ++i)
#pragma unroll
        for (int j = 0; j < 4; ++j) {
            int col = n0 + wc + j * 16 + l16;
            float b = bias[col];
#pragma unroll
            for (int r = 0; r < 4; ++r) {
                int row = m0 + wr + i * 16 + quad * 4 + r;
                float v = acc[i][j][r] + b;
                if (ACT == 1) {
                    v = fmaxf(v, 0.f);
                    ((__bf16*)Cp)[(size_t)row * N + col] = (__bf16)v;
                } else {
                    v = 1.f / (1.f + __expf(-v));
                    ((float*)Cp)[(size_t)row * N + col] = v;
                }
            }
        }
}

// ---------------------------------------------------------------------------
extern "C" void kernel_launch(void* const* d_in, const int* in_sizes, int n_in,
                              void* d_out, int out_size, void* d_ws, size_t ws_size,
                              hipStream_t stream)
{
    const float* x  = (const float*)d_in[0];
    const float* W1 = (const float*)d_in[1];
    const float* b1 = (const float*)d_in[2];
    const float* W2 = (const float*)d_in[3];
    const float* b2 = (const float*)d_in[4];
    const float* cb = (const float*)d_in[5];
    const float* W3 = (const float*)d_in[6];
    const float* b3 = (const float*)d_in[7];
    const float* W4 = (const float*)d_in[8];
    const float* b4 = (const float*)d_in[9];
    float* out = (float*)d_out;

    char* ws = (char*)d_ws;
    float*  h    = (float*)(ws);
    __bf16* h2b  = (__bf16*)(ws + 16777216ull);       // 64 MB
    float*  z32  = (float*)(ws + 134217728ull);       //  8 MB
    float*  zq   = (float*)(ws + 142606336ull);       //  8 MB
    _Float16* W1s = (_Float16*)(ws + 142606336ull);   //  8 MB (alias of zq)
    float*  nz32 = (float*)(ws + 150994944ull);       // 64 KB
    float*  cn32 = (float*)(ws + 151060480ull);       // 32 KB
    unsigned long long* gbest = (unsigned long long*)(ws + 151093248ull); // 128 KB
    double* acc  = (double*)(ws + 151224320ull);      // 8 B (4KB pad)
    float*  cnmax   = (float*)(ws + 151224328ull);    // 4 B (in acc pad)
    unsigned* listCnt = (unsigned*)(ws + 151224332ull); // 4 B (in acc pad)
    __bf16* W3t  = (__bf16*)(ws + 151228416ull);      // 512 KB [2048][128]
    __bf16* W4t  = (__bf16*)(ws + 151752704ull);      //   4 MB [1024][2048]
    _Float16* W2s = (_Float16*)(ws + 155947008ull);   //   1 MB [128][2*2048]

    _Float16* zh  = (_Float16*)(ws);                  // dead-h region (post-G2)
    _Float16* chh = (_Float16*)(ws + 4194304ull);
    unsigned long long* gbestA = (unsigned long long*)(ws + 6291456ull);
    unsigned* list = (unsigned*)(ws + 8388608ull);

    const unsigned long long XS_OFF = 157286400ull;   // 150 MB
    _Float16* xs = (_Float16*)(ws + XS_OFF);
    const bool pre_split_x = (ws_size >= XS_OFF + 67108864ull);

    init_scalars<<<1, 64, 0, stream>>>(acc, listCnt);
    init_gbest<<<B_ / 256, 256, 0, stream>>>(gbest);
    rownorm_kernel<<<KCB / 4, 256, 0, stream>>>(cb, cn32);
    cnmax_kernel<<<1, 256, 0, stream>>>(cn32, cnmax);
    transpose_to_bf16<<<dim3(DDIM / 32, HID / 32), 256, 0, stream>>>(W3, W3t, DDIM, HID);
    transpose_to_bf16<<<dim3(HID / 32, INDIM / 32), 256, 0, stream>>>(W4, W4t, HID, INDIM);
    transpose_split_f16<<<dim3(INDIM / 32, HID / 32), 256, 0, stream>>>(W1, W1s, INDIM, HID);
    transpose_split_f16<<<dim3(HID / 32, DDIM / 32), 256, 0, stream>>>(W2, W2s, HID, DDIM);

    // h = relu(x@W1 + b1), 3-pass split-fp16 MFMA  [16384,1024]x[1024,2048]
    if (pre_split_x) {
        split_x<<<(B_ * INDIM / 8) / 256, 256, 0, stream>>>(x, xs, B_ * INDIM / 8);
        gemm_split_pre<<<dim3(HID / 64, B_ / 128), 256, 0, stream>>>(
            xs, W1s, b1, h, B_, HID, INDIM);
    } else {
        gemm_split_f16<1, 3><<<dim3(HID / 64, B_ / 128), 256, 0, stream>>>(
            x, W1s, b1, h, B_, HID, INDIM);
    }
    // z32 = h@W2 + b2, 3-pass split-fp16 (K=64 promote) [16384,2048]x[2048,128]
    gemm_split_f16<0, 1><<<dim3(DDIM / 64, B_ / 128), 256, 0, stream>>>(
        h, W2s, b2, z32, B_, DDIM, HID);
    // nz32 = fl32(sum fl32(z^2))
    rownorm_kernel<<<B_ / 4, 256, 0, stream>>>(z32, nz32);

    // --- fast score path: N-loop fp16 sweeps + exact refine ---
    cvt_half<<<(B_ * DDIM / 8) / 256, 256, 0, stream>>>(z32, zh, 1.0f, B_ * DDIM / 8);
    cvt_half<<<(KCB * DDIM / 8) / 256, 256, 0, stream>>>(cb, chh, 4096.0f, KCB * DDIM / 8);
    score_sweep2<0><<<B_ / 32, 256, 0, stream>>>(
        zh, chh, nz32, cn32, gbestA, cnmax, listCnt, list);
    score_sweep2<1><<<B_ / 32, 256, 0, stream>>>(
        zh, chh, nz32, cn32, gbestA, cnmax, listCnt, list);
    refine_kernel<<<1024, 256, 0, stream>>>(z32, cb, nz32, cn32, listCnt, list, gbest);

    // z_q gather + commitment loss
    gather_zq_loss<<<B_ / 4, 256, 0, stream>>>(z32, cb, gbest, zq, acc);
    // h2 = relu(zq@W3 + b3) -> bf16               [16384,128]x[128,2048]
    gemm_mfma<true, 1><<<dim3(HID / 128, B_ / 128), 256, 0, stream>>>(
        (const void*)zq, W3t, b3, (void*)h2b, B_, HID, DDIM);
    // recon = sigmoid(h2@W4 + b4) -> fp32 out     [16384,2048]x[2048,1024]
    gemm_mfma<false, 2><<<dim3(INDIM / 128, B_ / 128), 256, 0, stream>>>(
        (const void*)h2b, W4t, b4, (void*)out, B_, INDIM, HID);

    finalize_kernel<<<B_ / 256, 256, 0, stream>>>(gbest, acc, out);
}